// Round 3
// baseline (291.882 us; speedup 1.0000x reference)
//
#include <hip/hip_runtime.h>
#include <math.h>

#define BATCH 16
#define TOPN 4
#define OUTS 224
#define PADW 224
#define IM 448
#define HP 896
#define NA 1614
#define IC1 2048
#define C128 128

// d_out float offsets
#define N_PART (BATCH*TOPN*3*OUTS*OUTS)       // 9,633,792
#define OFF_TOPIDX  (N_PART)
#define OFF_TOPPROB (N_PART + BATCH*TOPN)
#define OFF_SCORE   (N_PART + 2*BATCH*TOPN)

// ws float offsets.  d1 is [b][px 196][oc 128]
#define WS_D1 0
#define WS_IDX (BATCH*C128*196)                // 64 ints
#define WS_WT  (WS_IDX + 64)                   // repacked weights (ushort)
#define NWT1 (9*2048*128)
#define NWT2 (9*128*128)
#define NRPNT (BATCH*196*IC1)

typedef __attribute__((ext_vector_type(8))) short frag8;     // 8 bf16 (4 VGPRs)
typedef __attribute__((ext_vector_type(16))) float acc16;    // 16 fp32 acc (32x32)
typedef __attribute__((ext_vector_type(4)))  float acc4;     // 4 fp32 acc (16x16)

__device__ __forceinline__ unsigned short f2bf(float f) {
    unsigned int u = __float_as_uint(f);
    u = (u + 0x7fffu + ((u >> 16) & 1u)) >> 16;   // RNE
    return (unsigned short)u;
}
__device__ __forceinline__ float bf2f(unsigned short h) {
    return __uint_as_float(((unsigned int)h) << 16);
}
__device__ __forceinline__ void cvt4(const float* v, ushort4* h, ushort4* lo) {
    unsigned short hh[4], ll[4];
#pragma unroll
    for (int e = 0; e < 4; ++e) { hh[e] = f2bf(v[e]); ll[e] = f2bf(v[e] - bf2f(hh[e])); }
    *h  = make_ushort4(hh[0], hh[1], hh[2], hh[3]);
    *lo = make_ushort4(ll[0], ll[1], ll[2], ll[3]);
}

// ---------------- fused prep: wrepack(w1 frag-major, w2, w3) + rpn transpose + init d1 ----
__device__ __forceinline__ void wrepack_body(const float* __restrict__ w,
                                             unsigned short* __restrict__ w_hi,
                                             unsigned short* __restrict__ w_lo,
                                             int IC, int i) {
    if (i >= 128 * IC) return;
    int oc = i / IC, ic = i % IC;
    const float* src = w + (size_t)(oc * IC + ic) * 9;
#pragma unroll
    for (int tap = 0; tap < 9; ++tap) {
        float v = src[tap];
        unsigned short h = f2bf(v);
        size_t gi = ((size_t)tap * 128 + oc) * IC + ic;
        w_hi[gi] = h;
        w_lo[gi] = f2bf(v - bf2f(h));
    }
}

// w1 fragment-major repack: one frag8 (8 consecutive ic for one oc) per thread.
// dst frag index i layout: ((((t*16+kg)*2+h)*4+c)*4+ot)*64 + l   (l = q*32+ln)
//   oc = ot*32 + (l&31);  ic = kg*128 + h*64 + c*16 + (l>>5)*8 + e
__device__ __forceinline__ void w1frag_body(const float* __restrict__ w1,
                                            unsigned short* __restrict__ w1h,
                                            unsigned short* __restrict__ w1l,
                                            int i) {
    if (i >= 9 * 32768) return;
    int l  = i & 63;
    int ot = (i >> 6) & 3;
    int c  = (i >> 8) & 3;
    int h  = (i >> 10) & 1;
    int kg = (i >> 11) & 15;
    int t  = i >> 15;                      // 0..8
    int oc  = ot * 32 + (l & 31);
    int ic0 = kg * 128 + h * 64 + c * 16 + (l >> 5) * 8;
    const float* src = w1 + ((size_t)oc * IC1 + ic0) * 9 + t;
    frag8 hv, lv;
#pragma unroll
    for (int e = 0; e < 8; ++e) {
        float v = src[e * 9];
        unsigned short hs = f2bf(v);
        hv[e] = (short)hs;
        lv[e] = (short)f2bf(v - bf2f(hs));
    }
    size_t dst = (size_t)i * 8;
    *(frag8*)&w1h[dst] = hv;
    *(frag8*)&w1l[dst] = lv;
}

// grid 3360: [0,1152) w1frag | [1152,1216) w2 | [1216,1280) w3 | [1280,1792) rpnT | [1792,3360) init_d1
__global__ __launch_bounds__(256) void k_prep(
    const float* __restrict__ w1, unsigned short* __restrict__ w1h, unsigned short* __restrict__ w1l,
    const float* __restrict__ w2, unsigned short* __restrict__ w2h, unsigned short* __restrict__ w2l,
    const float* __restrict__ w3, unsigned short* __restrict__ w3h, unsigned short* __restrict__ w3l,
    const float* __restrict__ rpn, unsigned short* __restrict__ TH, unsigned short* __restrict__ TL,
    const float* __restrict__ b1, float* __restrict__ d1) {
    __shared__ float tile[64 * 201];
    const int tid = threadIdx.x;
    const int blk = blockIdx.x;
    if (blk < 1152) {
        w1frag_body(w1, w1h, w1l, blk * 256 + tid);
    } else if (blk < 1216) {
        wrepack_body(w2, w2h, w2l, C128, (blk - 1152) * 256 + tid);
    } else if (blk < 1280) {
        wrepack_body(w3, w3h, w3l, C128, (blk - 1216) * 256 + tid);
    } else if (blk < 1792) {
        const int bb = blk - 1280;
        const int b = bb & 15, icg = bb >> 4;
        const int ic0 = icg * 64;
        for (int qq = tid; qq < 3136; qq += 256) {
            int icl = qq / 49, r = qq % 49, p = r * 4;
            const float4 v = *(const float4*)&rpn[(size_t)(b * IC1 + ic0 + icl) * 196 + p];
            tile[icl * 201 + p + 0] = v.x;
            tile[icl * 201 + p + 1] = v.y;
            tile[icl * 201 + p + 2] = v.z;
            tile[icl * 201 + p + 3] = v.w;
        }
        __syncthreads();
        for (int qq = tid; qq < 3136; qq += 256) {
            int px = qq >> 4, ic4 = (qq & 15) * 4;
            float vv[4];
#pragma unroll
            for (int e = 0; e < 4; ++e) vv[e] = tile[(ic4 + e) * 201 + px];
            ushort4 h4, l4; cvt4(vv, &h4, &l4);
            size_t gi = (size_t)(b * 196 + px) * IC1 + ic0 + ic4;
            *(ushort4*)&TH[gi] = h4;
            *(ushort4*)&TL[gi] = l4;
        }
    } else {
        int i = (blk - 1792) * 256 + tid;
        if (i < BATCH * C128 * 196) d1[i] = b1[i & 127];
    }
}

// ---------------- conv1 via MFMA 32x32x16 bf16 ----------------
// Grid 512: blk = b*32 + kg*2 + half  (XCD = blk%8 = slice%8 -> weights L2-resident)
// 2 blocks/CU (64KB LDS, <=128 VGPR) -> 4 waves/SIMD; A in XOR-swizzled LDS;
// B reg-direct from L2 with explicit 1-deep prefetch pipeline.

#define LOADB(it, BH0, BH1, BL0, BL1) { \
    const int o_ = ((it) >> 2) * 262144 + ((it) & 3) * 2048; \
    BH0 = *(const frag8*)&WHb[o_];       BL0 = *(const frag8*)&WLb[o_]; \
    BH1 = *(const frag8*)&WHb[o_ + 512]; BL1 = *(const frag8*)&WLb[o_ + 512]; }

#define DOMFMA(it, BH0, BH1, BL0, BL1) { \
    const int tap_ = (it) >> 2; \
    const int off_ = (tap_ / 3) * 16 + (tap_ % 3); \
    const int kb_ = ((it) & 3) * 32 + q * 16; \
    const int p0_ = posa0 + off_, p1_ = posa1 + off_; \
    const int by0_ = (p0_ * 128 + kb_) ^ ((p0_ & 7) << 4); \
    const int by1_ = (p1_ * 128 + kb_) ^ ((p1_ & 7) << 4); \
    frag8 aH0 = *(const frag8*)((const char*)inH + by0_); \
    frag8 aL0 = *(const frag8*)((const char*)inL + by0_); \
    frag8 aH1 = *(const frag8*)((const char*)inH + by1_); \
    frag8 aL1 = *(const frag8*)((const char*)inL + by1_); \
    acc00 = __builtin_amdgcn_mfma_f32_32x32x16_bf16(aH0, BH0, acc00, 0, 0, 0); \
    acc00 = __builtin_amdgcn_mfma_f32_32x32x16_bf16(aH0, BL0, acc00, 0, 0, 0); \
    acc00 = __builtin_amdgcn_mfma_f32_32x32x16_bf16(aL0, BH0, acc00, 0, 0, 0); \
    acc01 = __builtin_amdgcn_mfma_f32_32x32x16_bf16(aH0, BH1, acc01, 0, 0, 0); \
    acc01 = __builtin_amdgcn_mfma_f32_32x32x16_bf16(aH0, BL1, acc01, 0, 0, 0); \
    acc01 = __builtin_amdgcn_mfma_f32_32x32x16_bf16(aL0, BH1, acc01, 0, 0, 0); \
    acc10 = __builtin_amdgcn_mfma_f32_32x32x16_bf16(aH1, BH0, acc10, 0, 0, 0); \
    acc10 = __builtin_amdgcn_mfma_f32_32x32x16_bf16(aH1, BL0, acc10, 0, 0, 0); \
    acc10 = __builtin_amdgcn_mfma_f32_32x32x16_bf16(aL1, BH0, acc10, 0, 0, 0); \
    acc11 = __builtin_amdgcn_mfma_f32_32x32x16_bf16(aH1, BH1, acc11, 0, 0, 0); \
    acc11 = __builtin_amdgcn_mfma_f32_32x32x16_bf16(aH1, BL1, acc11, 0, 0, 0); \
    acc11 = __builtin_amdgcn_mfma_f32_32x32x16_bf16(aL1, BH1, acc11, 0, 0, 0); }

__global__ __launch_bounds__(512, 4) void k_conv1_mfma(const unsigned short* __restrict__ rpnTH,
                                                       const unsigned short* __restrict__ rpnTL,
                                                       const unsigned short* __restrict__ wfh,
                                                       const unsigned short* __restrict__ wfl,
                                                       float* __restrict__ d1) {
    __shared__ unsigned short inH[256 * 64];   // [pos][ic64], XOR-swizzled, 32KB
    __shared__ unsigned short inL[256 * 64];

    const int tid = threadIdx.x;
    const int blk = blockIdx.x;
    const int b = blk >> 5, s = blk & 31;
    const int kg = s >> 1, half = s & 1;
    const int l = tid & 63, w = tid >> 6;
    const int ln = l & 31, q = l >> 5;
    const int mtw = w & 3, ntw = w >> 2;

    // zero LDS (halo rows/cols read as zeros)
    for (int i = tid; i < 2048; i += 512) {
        ((uint4*)inH)[i] = make_uint4(0u, 0u, 0u, 0u);
        ((uint4*)inL)[i] = make_uint4(0u, 0u, 0u, 0u);
    }

    acc16 acc00, acc01, acc10, acc11;
#pragma unroll
    for (int r = 0; r < 16; ++r) { acc00[r] = 0.f; acc01[r] = 0.f; acc10[r] = 0.f; acc11[r] = 0.f; }

    const int px0 = mtw * 64 + ln;
    const int px1 = mtw * 64 + 32 + ln;
    const int posa0 = (px0 < 196) ? ((px0 / 14) * 16 + (px0 % 14)) : 0;
    const int posa1 = (px1 < 196) ? ((px1 / 14) * 16 + (px1 % 14)) : 0;

    // fragment-major weight base: + tap*262144 + c*2048 + nt*512
    const unsigned short* WHb = wfh + (size_t)kg * 16384 + half * 8192 + ntw * 1024 + (size_t)l * 8;
    const unsigned short* WLb = wfl + (size_t)kg * 16384 + half * 8192 + ntw * 1024 + (size_t)l * 8;

    const int ics = kg * 128 + half * 64;
    __syncthreads();

    // stage A slice [196px][64ic] hi/lo into swizzled LDS
    for (int qq = tid; qq < 1568; qq += 512) {
        int px = qq >> 3, ic8 = qq & 7;
        size_t gi = (size_t)(b * 196 + px) * IC1 + ics + ic8 * 8;
        frag8 h8 = *(const frag8*)&rpnTH[gi];
        frag8 l8 = *(const frag8*)&rpnTL[gi];
        int pos = (px / 14 + 1) * 16 + (px % 14 + 1);
        int byo = (pos * 128 + ic8 * 16) ^ ((pos & 7) << 4);
        *(frag8*)((char*)inH + byo) = h8;
        *(frag8*)((char*)inL + byo) = l8;
    }
    __syncthreads();

    // 36 iterations (9 taps x 4 c), even/odd B double-buffer, barrier-free
    frag8 b0H0, b0H1, b0L0, b0L1, b1H0, b1H1, b1L0, b1L1;
    LOADB(0, b0H0, b0H1, b0L0, b0L1);
#pragma unroll
    for (int i2 = 0; i2 < 18; ++i2) {
        LOADB(i2 * 2 + 1, b1H0, b1H1, b1L0, b1L1);
        DOMFMA(i2 * 2, b0H0, b0H1, b0L0, b0L1);
        if (i2 < 17) LOADB(i2 * 2 + 2, b0H0, b0H1, b0L0, b0L1);
        DOMFMA(i2 * 2 + 1, b1H0, b1H1, b1L0, b1L1);
    }

    // epilogue: atomic partial-sum into d1
    {
        const int oc0 = ntw * 64 + ln;
        const int oc1 = ntw * 64 + 32 + ln;
#pragma unroll
        for (int r = 0; r < 16; ++r) {
            int m = (r & 3) + 8 * (r >> 2) + 4 * q;
            int pxa = mtw * 64 + m;
            int pxb = mtw * 64 + 32 + m;
            if (pxa < 196) {
                atomicAdd(&d1[(size_t)(b * 196 + pxa) * 128 + oc0], acc00[r]);
                atomicAdd(&d1[(size_t)(b * 196 + pxa) * 128 + oc1], acc01[r]);
            }
            if (pxb < 196) {
                atomicAdd(&d1[(size_t)(b * 196 + pxb) * 128 + oc0], acc10[r]);
                atomicAdd(&d1[(size_t)(b * 196 + pxb) * 128 + oc1], acc11[r]);
            }
        }
    }
}

// ---------------- fused tail: conv2+conv3+tidy+NMS, one 512-thread block per batch -------
__global__ __launch_bounds__(512, 1) void k_tail(
    const float* __restrict__ d1,
    const unsigned short* __restrict__ w2h, const unsigned short* __restrict__ w2l,
    const unsigned short* __restrict__ w3h, const unsigned short* __restrict__ w3l,
    const float* __restrict__ b2, const float* __restrict__ b3,
    const float* __restrict__ wt1, const float* __restrict__ bt1,
    const float* __restrict__ wt2, const float* __restrict__ bt2,
    const float* __restrict__ wt3, const float* __restrict__ bt3,
    const int* __restrict__ anchors,
    float* __restrict__ score_out, float* __restrict__ out_idx,
    float* __restrict__ out_prob, int* __restrict__ idx_ws) {
    extern __shared__ char smem[];
    unsigned short* inH = (unsigned short*)(smem);            // [pos 304][ic 72]
    unsigned short* inL = (unsigned short*)(smem + 43776);
    unsigned short* wHs = (unsigned short*)(smem + 87552);    // [oc 128][ic 72]
    unsigned short* wLs = (unsigned short*)(smem + 105984);
    unsigned short* t1H = (unsigned short*)(smem + 124416);   // [oc16][ic 72]
    unsigned short* t1L = (unsigned short*)(smem + 126720);
    float*  d2f  = (float*)(smem + 129024);                   // [px 49][oc 128]
    float*  sbuf = (float*)(smem + 154112);                   // [1614]
    unsigned short* dhH = (unsigned short*)(smem);            // [pos 192][ic 72]
    unsigned short* dhL = (unsigned short*)(smem + 27648);
    float*  d3f  = (float*)(smem + 55296);                    // [oc 128][px 16]
    unsigned short* t2H = (unsigned short*)(smem + 63488);
    unsigned short* t2L = (unsigned short*)(smem + 65792);
    unsigned short* w3H = (unsigned short*)(smem + 68096);
    unsigned short* w3L = (unsigned short*)(smem + 86528);
    float* wt3s = (float*)(smem);
    float* y0s = (float*)(smem + 6464);
    float* x0s = (float*)(smem + 12928);
    float* y1s = (float*)(smem + 19392);
    float* x1s = (float*)(smem + 25856);
    float* ars = (float*)(smem + 32320);
    float* rv  = (float*)(smem + 38784);
    int*   ri  = (int*)(smem + 39808);

    const int tid = threadIdx.x;           // 0..511, 8 waves
    const int b = blockIdx.x;
    const int l = tid & 63, w = tid >> 6;
    const int ln = l & 31, q = l >> 5;
    const int l16 = l & 15, q4 = l >> 4;

    // ================= phase A: conv2 + t1 =================
    for (int i = tid; i < 304 * 72; i += 512) { inH[i] = 0; inL[i] = 0; }

    acc16 c2;
    acc4 t1a[2];
#pragma unroll
    for (int r = 0; r < 16; ++r) c2[r] = 0.f;
#pragma unroll
    for (int i = 0; i < 2; ++i)
#pragma unroll
        for (int r = 0; r < 4; ++r) t1a[i][r] = 0.f;

    const int mtw = w & 1, ntw = w >> 1;   // 2 px-tiles x 4 oc-tiles
    int posa2;
    {
        int px = mtw * 32 + ln;
        posa2 = (px < 49) ? ((px / 7) * 32 + (px % 7) * 2) : 256;
    }
    __syncthreads();

    for (int half = 0; half < 2; ++half) {
        const int ics = half * 64;
        for (int qq = tid; qq < 3136; qq += 512) {
            int px = qq >> 4, ic4 = (qq & 15) * 4;
            float4 v = *(const float4*)&d1[(size_t)(b * 196 + px) * 128 + ics + ic4];
            float vv[4] = {fmaxf(v.x, 0.f), fmaxf(v.y, 0.f), fmaxf(v.z, 0.f), fmaxf(v.w, 0.f)};
            ushort4 h4, l4; cvt4(vv, &h4, &l4);
            int pos = (px / 14 + 1) * 16 + (px % 14 + 1);
            *(ushort4*)&inH[pos * 72 + ic4] = h4;
            *(ushort4*)&inL[pos * 72 + ic4] = l4;
        }
        for (int qq = tid; qq < 1024; qq += 512) {
            int m = qq >> 6, k = qq & 63;
            float v = (m < 6) ? wt1[m * 128 + ics + k] : 0.f;
            unsigned short h = f2bf(v);
            t1H[m * 72 + k] = h;
            t1L[m * 72 + k] = f2bf(v - bf2f(h));
        }
        // prefetch tap-0 conv2 weights
        ushort4 pwh[4], pwl[4];
#pragma unroll
        for (int it = 0; it < 4; ++it) {
            int qq = tid + it * 512;
            int oc = qq >> 4, ic4 = (qq & 15) * 4;
            size_t gi = ((size_t)(0 * 128 + oc)) * C128 + ics + ic4;
            pwh[it] = *(const ushort4*)&w2h[gi];
            pwl[it] = *(const ushort4*)&w2l[gi];
        }
        __syncthreads();

        for (int tap = 0; tap < 9; ++tap) {
#pragma unroll
            for (int it = 0; it < 4; ++it) {
                int qq = tid + it * 512;
                int oc = qq >> 4, ic4 = (qq & 15) * 4;
                *(ushort4*)&wHs[oc * 72 + ic4] = pwh[it];
                *(ushort4*)&wLs[oc * 72 + ic4] = pwl[it];
            }
            if (tap < 8) {
#pragma unroll
                for (int it = 0; it < 4; ++it) {
                    int qq = tid + it * 512;
                    int oc = qq >> 4, ic4 = (qq & 15) * 4;
                    size_t gi = ((size_t)((tap + 1) * 128 + oc)) * C128 + ics + ic4;
                    pwh[it] = *(const ushort4*)&w2h[gi];
                    pwl[it] = *(const ushort4*)&w2l[gi];
                }
            }
            __syncthreads();
            const int off = (tap / 3) * 16 + (tap % 3);
#pragma unroll
            for (int c = 0; c < 4; ++c) {
                const int ko = c * 16 + q * 8;
                int pp = (posa2 + off) * 72 + ko;
                frag8 aH = *(const frag8*)&inH[pp];
                frag8 aL = *(const frag8*)&inL[pp];
                int oc = ntw * 32 + ln;
                frag8 bH = *(const frag8*)&wHs[oc * 72 + ko];
                frag8 bL = *(const frag8*)&wLs[oc * 72 + ko];
                c2 = __builtin_amdgcn_mfma_f32_32x32x16_bf16(aH, bH, c2, 0, 0, 0);
                c2 = __builtin_amdgcn_mfma_f32_32x32x16_bf16(aH, bL, c2, 0, 0, 0);
                c2 = __builtin_amdgcn_mfma_f32_32x32x16_bf16(aL, bH, c2, 0, 0, 0);
            }
            __syncthreads();
        }

        // t1 MFMA on this half (inH intact since last barrier)
#pragma unroll
        for (int i = 0; i < 2; ++i) {
            int px = (w * 2 + i) * 16 + l16;
            int pos = (px < 196) ? ((px / 14 + 1) * 16 + (px % 14 + 1)) : 256;
#pragma unroll
            for (int c = 0; c < 2; ++c) {
                int ko = c * 32 + q4 * 8;
                frag8 aH = *(const frag8*)&t1H[l16 * 72 + ko];
                frag8 aL = *(const frag8*)&t1L[l16 * 72 + ko];
                frag8 bH = *(const frag8*)&inH[pos * 72 + ko];
                frag8 bL = *(const frag8*)&inL[pos * 72 + ko];
                t1a[i] = __builtin_amdgcn_mfma_f32_16x16x32_bf16(aH, bH, t1a[i], 0, 0, 0);
                t1a[i] = __builtin_amdgcn_mfma_f32_16x16x32_bf16(aH, bL, t1a[i], 0, 0, 0);
                t1a[i] = __builtin_amdgcn_mfma_f32_16x16x32_bf16(aL, bH, t1a[i], 0, 0, 0);
            }
        }
        __syncthreads();
    }

    // conv2 epilogue -> d2f[px][oc]
    {
        int oc = ntw * 32 + ln;
        float bias = b2[oc];
#pragma unroll
        for (int r = 0; r < 16; ++r) {
            int m = (r & 3) + 8 * (r >> 2) + 4 * q;
            int px = mtw * 32 + m;
            if (px < 49) d2f[px * 128 + oc] = fmaxf(c2[r] + bias, 0.f);
        }
    }
    // t1 epilogue -> scores
#pragma unroll
    for (int i = 0; i < 2; ++i) {
        int px = (w * 2 + i) * 16 + l16;
#pragma unroll
        for (int r = 0; r < 4; ++r) {
            int oc = q4 * 4 + r;
            if (oc < 6 && px < 196) {
                float v = t1a[i][r] + bt1[oc];
                sbuf[oc * 196 + px] = v;
                score_out[b * NA + oc * 196 + px] = v;
            }
        }
    }
    __syncthreads();

    // ================= phase B: conv3 (waves 0-3) + t2 (waves 4-7) =================
    for (int i = tid; i < 192 * 72; i += 512) { dhH[i] = 0; dhL[i] = 0; }

    acc16 c3;
    acc4 t2a;
#pragma unroll
    for (int r = 0; r < 16; ++r) c3[r] = 0.f;
#pragma unroll
    for (int r = 0; r < 4; ++r) t2a[r] = 0.f;

    const int posb3 = (ln < 16) ? ((ln / 4) * 32 + (ln % 4) * 2) : 144;
    const int pxt2 = (w - 4) * 16 + l16;   // valid for w>=4
    const int posbt2 = (w >= 4 && pxt2 < 49) ? ((pxt2 / 7 + 1) * 16 + (pxt2 % 7 + 1)) : 144;
    __syncthreads();

    for (int half = 0; half < 2; ++half) {
        const int ics = half * 64;
        for (int qq = tid; qq < 784; qq += 512) {
            int px = qq >> 4, ic4 = (qq & 15) * 4;
            float4 v = *(const float4*)&d2f[px * 128 + ics + ic4];
            float vv[4] = {v.x, v.y, v.z, v.w};
            ushort4 h4, l4; cvt4(vv, &h4, &l4);
            int pos = (px / 7 + 1) * 16 + (px % 7 + 1);
            *(ushort4*)&dhH[pos * 72 + ic4] = h4;
            *(ushort4*)&dhL[pos * 72 + ic4] = l4;
        }
        for (int qq = tid; qq < 1024; qq += 512) {
            int m = qq >> 6, k = qq & 63;
            float v = (m < 6) ? wt2[m * 128 + ics + k] : 0.f;
            unsigned short h = f2bf(v);
            t2H[m * 72 + k] = h;
            t2L[m * 72 + k] = f2bf(v - bf2f(h));
        }
        ushort4 pwh[4], pwl[4];
#pragma unroll
        for (int it = 0; it < 4; ++it) {
            int qq = tid + it * 512;
            int oc = qq >> 4, ic4 = (qq & 15) * 4;
            size_t gi = ((size_t)(0 * 128 + oc)) * C128 + ics + ic4;
            pwh[it] = *(const ushort4*)&w3h[gi];
            pwl[it] = *(const ushort4*)&w3l[gi];
        }
        __syncthreads();

        for (int tap = 0; tap < 9; ++tap) {
#pragma unroll
            for (int it = 0; it < 4; ++it) {
                int qq = tid + it * 512;
                int oc = qq >> 4, ic4 = (qq & 15) * 4;
                *(ushort4*)&w3H[oc * 72 + ic4] = pwh[it];
                *(ushort4*)&w3L[oc * 72 + ic4] = pwl[it];
            }
            if (tap < 8) {
#pragma unroll
                for (int it = 0; it < 4; ++it) {
                    int qq = tid + it * 512;
                    int oc = qq >> 4, ic4 = (qq & 15) * 4;
                    size_t gi = ((size_t)((tap + 1) * 128 + oc)) * C128 + ics + ic4;
                    pwh[it] = *(const ushort4*)&w3h[gi];
                    pwl[it] = *(const ushort4*)&w3l[gi];
                }
            }
            __syncthreads();
            const int off = (tap / 3) * 16 + (tap % 3);
            if (w < 4) {
#pragma unroll
                for (int c = 0; c < 4; ++c) {
                    const int ko = c * 16 + q * 8;
                    int pp = (posb3 + off) * 72 + ko;
                    frag8 aH = *(const frag8*)&dhH[pp];
                    frag8 aL = *(const frag8*)&dhL[pp];
                    int oc = w * 32 + ln;
                    frag8 bH = *(const frag8*)&w3H[oc * 72 + ko];
                    frag8 bL = *(const frag8*)&w3L[oc * 72 + ko];
                    c3 = __builtin_amdgcn_mfma_f32_32x32x16_bf16(aH, bH, c3, 0, 0, 0);
                    c3 = __builtin_amdgcn_mfma_f32_32x32x16_bf16(aH, bL, c3, 0, 0, 0);
                    c3 = __builtin_amdgcn_mfma_f32_32x32x16_bf16(aL, bH, c3, 0, 0, 0);
                }
            } else if (tap == 0) {
                // t2 on this half (dh is stable during the tap loop)
#pragma unroll
                for (int c = 0; c < 2; ++c) {
                    int ko = c * 32 + q4 * 8;
                    frag8 aH = *(const frag8*)&t2H[l16 * 72 + ko];
                    frag8 aL = *(const frag8*)&t2L[l16 * 72 + ko];
                    frag8 bH = *(const frag8*)&dhH[posbt2 * 72 + ko];
                    frag8 bL = *(const frag8*)&dhL[posbt2 * 72 + ko];
                    t2a = __builtin_amdgcn_mfma_f32_16x16x32_bf16(aH, bH, t2a, 0, 0, 0);
                    t2a = __builtin_amdgcn_mfma_f32_16x16x32_bf16(aH, bL, t2a, 0, 0, 0);
                    t2a = __builtin_amdgcn_mfma_f32_16x16x32_bf16(aL, bH, t2a, 0, 0, 0);
                }
            }
            __syncthreads();
        }
    }

    // conv3 epilogue -> d3f[oc][px]
    if (w < 4) {
        int oc = w * 32 + ln;
        float bias = b3[oc];
#pragma unroll
        for (int r = 0; r < 16; ++r) {
            int px = (r & 3) + 8 * (r >> 2) + 4 * q;
            if (px < 16) d3f[oc * 16 + px] = fmaxf(c3[r] + bias, 0.f);
        }
    } else {
        // t2 epilogue -> scores
#pragma unroll
        for (int r = 0; r < 4; ++r) {
            int oc = q4 * 4 + r;
            if (oc < 6 && pxt2 < 49) {
                float v = t2a[r] + bt2[oc];
                sbuf[1176 + oc * 49 + pxt2] = v;
                score_out[b * NA + 1176 + oc * 49 + pxt2] = v;
            }
        }
    }
    for (int i = tid; i < 1152; i += 512) wt3s[i] = wt3[i];
    __syncthreads();

    // ================= phase C: t3 (VALU) + anchor staging =================
    if (tid < 144) {
        int oc = tid >> 4, px = tid & 15;
        float s = bt3[oc];
        for (int ic = 0; ic < 128; ++ic) s += wt3s[oc * 128 + ic] * d3f[ic * 16 + px];
        sbuf[1470 + oc * 16 + px] = s;
        score_out[b * NA + 1470 + oc * 16 + px] = s;
    }
    for (int j = tid; j < NA; j += 512) {
        int4 a = ((const int4*)anchors)[j];
        float a0 = (float)a.x, a1 = (float)a.y, a2 = (float)a.z, a3 = (float)a.w;
        y0s[j] = a0; x0s[j] = a1; y1s[j] = a2; x1s[j] = a3;
        ars[j] = (a2 - a0) * (a3 - a1);
    }
    __syncthreads();

    // ================= phase D: greedy hard-NMS top-4 (shuffle reduce) =================
    for (int it = 0; it < TOPN; ++it) {
        float bv = -INFINITY; int bi = NA;
        for (int j = tid; j < NA; j += 512) {
            float v = sbuf[j];
            if (v > bv || (v == bv && j < bi)) { bv = v; bi = j; }
        }
#pragma unroll
        for (int d = 1; d < 64; d <<= 1) {
            float ov = __shfl_xor(bv, d, 64);
            int   oi = __shfl_xor(bi, d, 64);
            if (ov > bv || (ov == bv && oi < bi)) { bv = ov; bi = oi; }
        }
        if (l == 0) { rv[w] = bv; ri[w] = bi; }
        __syncthreads();
        if (tid == 0) {
            float V = rv[0]; int K = ri[0];
#pragma unroll
            for (int j = 1; j < 8; ++j) {
                float ov = rv[j]; int oi = ri[j];
                if (ov > V || (ov == V && oi < K)) { V = ov; K = oi; }
            }
            ri[8] = K;
            out_idx[b * TOPN + it] = (float)K;
            out_prob[b * TOPN + it] = V;
            idx_ws[b * TOPN + it] = K;
        }
        __syncthreads();
        int K = ri[8];
        float ky0 = y0s[K], kx0 = x0s[K], ky1 = y1s[K], kx1 = x1s[K], ka = ars[K];
        for (int j = tid; j < NA; j += 512) {
            float iy = fmaxf(fminf(y1s[j], ky1) - fmaxf(y0s[j], ky0), 0.f);
            float ix = fmaxf(fminf(x1s[j], kx1) - fmaxf(x0s[j], kx0), 0.f);
            float inter = iy * ix;
            float iou = inter / (ars[j] + ka - inter);
            if (iou >= 0.25f) sbuf[j] = -INFINITY;
        }
        __syncthreads();
    }
}

// ---------------- bilinear crop-resize ----------------
__global__ __launch_bounds__(256) void k_crop(const float* __restrict__ x,
                                              const int* __restrict__ anchors,
                                              const int* __restrict__ idx_ws,
                                              float* __restrict__ out) {
    int blk = blockIdx.x;
    int crop = blk / OUTS;
    int i = blk % OUTS;
    int j = threadIdx.x;
    if (j >= OUTS) return;
    int b = crop >> 2;
    int a = idx_ws[crop];
    int y0 = anchors[a * 4], x0 = anchors[a * 4 + 1];
    int y1 = anchors[a * 4 + 2], x1 = anchors[a * 4 + 3];

    float ti = (float)i / 223.f;
    float ys = (float)y0 + ti * (float)(y1 - y0 - 1);
    int yi0 = (int)ys;
    int yi1 = min(yi0 + 1, HP - 1);
    float wy = ys - (float)yi0;

    float tj = (float)j / 223.f;
    float xs = (float)x0 + tj * (float)(x1 - x0 - 1);
    int xi0 = (int)xs;
    int xi1 = min(xi0 + 1, HP - 1);
    float wx = xs - (float)xi0;

    int ry0 = yi0 - PADW, ry1 = yi1 - PADW, rx0 = xi0 - PADW, rx1 = xi1 - PADW;
    bool vy0 = (ry0 >= 0) && (ry0 < IM), vy1 = (ry1 >= 0) && (ry1 < IM);
    bool vx0 = (rx0 >= 0) && (rx0 < IM), vx1 = (rx1 >= 0) && (rx1 < IM);

    float w00 = (1.f - wy) * (1.f - wx), w01 = (1.f - wy) * wx;
    float w10 = wy * (1.f - wx), w11 = wy * wx;

#pragma unroll
    for (int c = 0; c < 3; ++c) {
        const float* xp = x + (size_t)(b * 3 + c) * IM * IM;
        float g00 = (vy0 && vx0) ? xp[ry0 * IM + rx0] : 0.f;
        float g01 = (vy0 && vx1) ? xp[ry0 * IM + rx1] : 0.f;
        float g10 = (vy1 && vx0) ? xp[ry1 * IM + rx0] : 0.f;
        float g11 = (vy1 && vx1) ? xp[ry1 * IM + rx1] : 0.f;
        out[(size_t)(crop * 3 + c) * OUTS * OUTS + i * OUTS + j] =
            g00 * w00 + g01 * w01 + g10 * w10 + g11 * w11;
    }
}

extern "C" void kernel_launch(void* const* d_in, const int* in_sizes, int n_in,
                              void* d_out, int out_size, void* d_ws, size_t ws_size,
                              hipStream_t stream) {
    (void)in_sizes; (void)n_in; (void)out_size; (void)ws_size;
    const float* x    = (const float*)d_in[0];
    const float* rpn  = (const float*)d_in[1];
    const float* w1   = (const float*)d_in[2];
    const float* b1   = (const float*)d_in[3];
    const float* w2   = (const float*)d_in[4];
    const float* b2   = (const float*)d_in[5];
    const float* w3   = (const float*)d_in[6];
    const float* b3   = (const float*)d_in[7];
    const float* wt1  = (const float*)d_in[8];
    const float* bt1  = (const float*)d_in[9];
    const float* wt2  = (const float*)d_in[10];
    const float* bt2  = (const float*)d_in[11];
    const float* wt3  = (const float*)d_in[12];
    const float* bt3  = (const float*)d_in[13];
    const int*   anc  = (const int*)d_in[14];

    float* out = (float*)d_out;
    float* ws  = (float*)d_ws;
    float* d1  = ws + WS_D1;
    int*   idxw = (int*)(ws + WS_IDX);
    unsigned short* w1h = (unsigned short*)(ws + WS_WT);
    unsigned short* w1l = w1h + NWT1;
    unsigned short* w2h = w1l + NWT1;
    unsigned short* w2l = w2h + NWT2;
    unsigned short* w3h = w2l + NWT2;
    unsigned short* w3l = w3h + NWT2;
    unsigned short* rpnTH = w3l + NWT2;
    unsigned short* rpnTL = rpnTH + NRPNT;

    static const int TAIL_LDS = 160568;
    hipFuncSetAttribute((const void*)k_tail, hipFuncAttributeMaxDynamicSharedMemorySize, TAIL_LDS);

    k_prep<<<3360, 256, 0, stream>>>(w1, w1h, w1l, w2, w2h, w2l, w3, w3h, w3l,
                                     rpn, rpnTH, rpnTL, b1, d1);
    k_conv1_mfma<<<512, 512, 0, stream>>>(rpnTH, rpnTL, w1h, w1l, d1);
    k_tail<<<BATCH, 512, TAIL_LDS, stream>>>(d1, w2h, w2l, w3h, w3l, b2, b3,
                                             wt1, bt1, wt2, bt2, wt3, bt3, anc,
                                             out + OFF_SCORE, out + OFF_TOPIDX,
                                             out + OFF_TOPPROB, idxw);
    k_crop<<<BATCH * TOPN * OUTS, 256, 0, stream>>>(x, anc, idxw, out);
}

// Round 5
// 273.892 us; speedup vs baseline: 1.0657x; 1.0657x over previous
//
#include <hip/hip_runtime.h>
#include <math.h>

#define BATCH 16
#define TOPN 4
#define OUTS 224
#define PADW 224
#define IM 448
#define HP 896
#define NA 1614
#define IC1 2048
#define C128 128

// d_out float offsets
#define N_PART (BATCH*TOPN*3*OUTS*OUTS)       // 9,633,792
#define OFF_TOPIDX  (N_PART)
#define OFF_TOPPROB (N_PART + BATCH*TOPN)
#define OFF_SCORE   (N_PART + 2*BATCH*TOPN)

// ws float offsets.  d1 is [b][px 196][oc 128]
#define WS_D1 0
#define WS_IDX (BATCH*C128*196)                // 64 ints
#define WS_WT  (WS_IDX + 64)                   // repacked weights (ushort)
#define NWT1 (9*2048*128)
#define NWT2 (9*128*128)
#define NIMG (16*32*16384)                     // pre-swizzled conv1 input images (ushort)

typedef __attribute__((ext_vector_type(8))) short frag8;     // 8 bf16 (4 VGPRs)
typedef __attribute__((ext_vector_type(16))) float acc16;    // 16 fp32 acc (32x32)
typedef __attribute__((ext_vector_type(4)))  float acc4;     // 4 fp32 acc (16x16)

__device__ __forceinline__ unsigned short f2bf(float f) {
    unsigned int u = __float_as_uint(f);
    u = (u + 0x7fffu + ((u >> 16) & 1u)) >> 16;   // RNE
    return (unsigned short)u;
}
__device__ __forceinline__ float bf2f(unsigned short h) {
    return __uint_as_float(((unsigned int)h) << 16);
}
__device__ __forceinline__ void cvt4(const float* v, ushort4* h, ushort4* lo) {
    unsigned short hh[4], ll[4];
#pragma unroll
    for (int e = 0; e < 4; ++e) { hh[e] = f2bf(v[e]); ll[e] = f2bf(v[e] - bf2f(hh[e])); }
    *h  = make_ushort4(hh[0], hh[1], hh[2], hh[3]);
    *lo = make_ushort4(ll[0], ll[1], ll[2], ll[3]);
}

// ---------------- fused prep ----------------
__device__ __forceinline__ void wrepack_body(const float* __restrict__ w,
                                             unsigned short* __restrict__ w_hi,
                                             unsigned short* __restrict__ w_lo,
                                             int IC, int i) {
    if (i >= 128 * IC) return;
    int oc = i / IC, ic = i % IC;
    const float* src = w + (size_t)(oc * IC + ic) * 9;
#pragma unroll
    for (int tap = 0; tap < 9; ++tap) {
        float v = src[tap];
        unsigned short h = f2bf(v);
        size_t gi = ((size_t)tap * 128 + oc) * IC + ic;
        w_hi[gi] = h;
        w_lo[gi] = f2bf(v - bf2f(h));
    }
}

// w1 fragment-major repack, one (oc, 8-ic) pair per thread, all 9 taps.
// Thread reads a CONTIGUOUS 288B run of w1; each HBM byte fetched once.
// dst element = t*262144 + kg*16384 + h*8192 + c*2048 + ot*512 + l*8
//   with oc = ot*32 + (l&31), ic = kg*128 + h*64 + c*16 + (l>>5)*8 + e
__device__ __forceinline__ void w1frag_body(const float* __restrict__ w1,
                                            unsigned short* __restrict__ w1h,
                                            unsigned short* __restrict__ w1l,
                                            int i) {
    if (i >= 32768) return;
    int oc5 = i & 31;
    int q8  = (i >> 5) & 1;
    int ot  = (i >> 6) & 3;
    int c   = (i >> 8) & 3;
    int h   = (i >> 10) & 1;
    int kg  = (i >> 11) & 15;
    int oc  = ot * 32 + oc5;
    int ic0 = kg * 128 + h * 64 + c * 16 + q8 * 8;
    int l   = q8 * 32 + oc5;
    const float* src = w1 + ((size_t)oc * IC1 + ic0) * 9;
    size_t dbase = (size_t)kg * 16384 + h * 8192 + c * 2048 + ot * 512 + l * 8;
#pragma unroll
    for (int t = 0; t < 9; ++t) {
        frag8 hv, lv;
#pragma unroll
        for (int e = 0; e < 8; ++e) {
            float v = src[e * 9 + t];
            unsigned short hs = f2bf(v);
            hv[e] = (short)hs;
            lv[e] = (short)f2bf(v - bf2f(hs));
        }
        size_t dst = dbase + (size_t)t * 262144;
        *(frag8*)&w1h[dst] = hv;
        *(frag8*)&w1l[dst] = lv;
    }
}

// grid 1160: [0,128) w1frag | [128,192) w2 | [192,256) w3 | [256,768) img | [768,1160) init_d1
__global__ __launch_bounds__(256) void k_prep(
    const float* __restrict__ w1, unsigned short* __restrict__ w1h, unsigned short* __restrict__ w1l,
    const float* __restrict__ w2, unsigned short* __restrict__ w2h, unsigned short* __restrict__ w2l,
    const float* __restrict__ w3, unsigned short* __restrict__ w3h, unsigned short* __restrict__ w3l,
    const float* __restrict__ rpn, unsigned short* __restrict__ imgH,
    const float* __restrict__ b1, float* __restrict__ d1) {
    __shared__ float tile[64 * 201];
    const int tid = threadIdx.x;
    const int blk = blockIdx.x;
    if (blk < 128) {
        w1frag_body(w1, w1h, w1l, blk * 256 + tid);
    } else if (blk < 192) {
        wrepack_body(w2, w2h, w2l, C128, (blk - 128) * 256 + tid);
    } else if (blk < 256) {
        wrepack_body(w3, w3h, w3l, C128, (blk - 192) * 256 + tid);
    } else if (blk < 768) {
        // build pre-swizzled 32KB image for slice (b, icg): [256 pos][64 ic] bf16-hi
        const int bb = blk - 256;
        const int b = bb & 15, icg = bb >> 4;
        const int ic0 = icg * 64;
        char* img = (char*)(imgH + (size_t)bb * 16384);   // slice index = icg*16 + b
        for (int qq = tid; qq < 3136; qq += 256) {
            int icl = qq / 49, r = qq % 49, p = r * 4;
            const float4 v = *(const float4*)&rpn[(size_t)(b * IC1 + ic0 + icl) * 196 + p];
            tile[icl * 201 + p + 0] = v.x;
            tile[icl * 201 + p + 1] = v.y;
            tile[icl * 201 + p + 2] = v.z;
            tile[icl * 201 + p + 3] = v.w;
        }
        __syncthreads();
        // data cells: pos = (px/14+1)*16 + (px%14+1), XOR-swizzled byte layout
        for (int qq = tid; qq < 3136; qq += 256) {
            int px = qq >> 4, ic4 = (qq & 15) * 4;
            float vv[4];
            unsigned short hh[4];
#pragma unroll
            for (int e = 0; e < 4; ++e) { vv[e] = tile[(ic4 + e) * 201 + px]; hh[e] = f2bf(vv[e]); }
            int pos = (px / 14 + 1) * 16 + (px % 14 + 1);
            int byo = (pos * 128 + ic4 * 2) ^ ((pos & 7) << 4);
            *(ushort4*)(img + byo) = make_ushort4(hh[0], hh[1], hh[2], hh[3]);
        }
        // halo cells: 60 positions, zero full 128B rows (swizzle-invariant)
        for (int qq = tid; qq < 960; qq += 256) {
            int hp = qq >> 4, sub = qq & 15;
            int pos;
            if (hp < 16)      pos = hp;                       // row 0
            else if (hp < 32) pos = 240 + (hp - 16);          // row 15
            else if (hp < 46) pos = (hp - 31) * 16;           // col 0, rows 1..14
            else              pos = (hp - 45) * 16 + 15;      // col 15, rows 1..14
            *(ushort4*)(img + pos * 128 + sub * 8) = make_ushort4(0, 0, 0, 0);
        }
    } else {
        int i = (blk - 768) * 256 + tid;     // one float4 per thread, 392 blocks exactly
        int base = i * 4;
        float4 v;
        v.x = b1[(base + 0) & 127]; v.y = b1[(base + 1) & 127];
        v.z = b1[(base + 2) & 127]; v.w = b1[(base + 3) & 127];
        *(float4*)&d1[base] = v;
    }
}

// ---------------- conv1 via MFMA 32x32x16 bf16, 2-term (input bf16, weight hi+lo) -------
// Grid 512: blk = b*32 + icg  (XCD = icg%8 -> per-XCD weight set 4 slices = 1.2MB, L2-hot)
// Wave tile 128px x 32oc (mtw 2 x ntw 4); per iter: 4 A-ds + 2 B-vmem + 8 MFMA.
// A staged as a linear copy of the pre-swizzled image; no zero-init, no barriers in loop.

#define LOADB(it, BH, BL) { \
    const int o_ = ((it) >> 2) * 262144 + ((it) & 3) * 2048; \
    BH = *(const frag8*)&WHb[o_]; BL = *(const frag8*)&WLb[o_]; }

#define DOMFMA(it, BH, BL) { \
    const int tap_ = (it) >> 2; \
    const int off_ = (tap_ / 3) * 16 + (tap_ % 3); \
    const int kb_ = ((it) & 3) * 32 + q * 16; \
    frag8 aH[4]; \
    _Pragma("unroll") \
    for (int mt_ = 0; mt_ < 4; ++mt_) { \
        const int p_ = posa[mt_] + off_; \
        const int by_ = (p_ * 128 + kb_) ^ ((p_ & 7) << 4); \
        aH[mt_] = *(const frag8*)((const char*)inH + by_); \
    } \
    _Pragma("unroll") \
    for (int mt_ = 0; mt_ < 4; ++mt_) { \
        acc[mt_] = __builtin_amdgcn_mfma_f32_32x32x16_bf16(aH[mt_], BH, acc[mt_], 0, 0, 0); \
        acc[mt_] = __builtin_amdgcn_mfma_f32_32x32x16_bf16(aH[mt_], BL, acc[mt_], 0, 0, 0); \
    } }

__global__ __launch_bounds__(512, 4) void k_conv1_mfma(const unsigned short* __restrict__ imgH,
                                                       const unsigned short* __restrict__ wfh,
                                                       const unsigned short* __restrict__ wfl,
                                                       float* __restrict__ d1) {
    __shared__ unsigned short inH[256 * 64];   // 32KB pre-swizzled [pos][ic64] bf16-hi

    const int tid = threadIdx.x;
    const int blk = blockIdx.x;
    const int b = blk >> 5;
    const int icg = blk & 31;
    const int l = tid & 63, w = tid >> 6;
    const int ln = l & 31, q = l >> 5;
    const int mtw = w & 1, ntw = w >> 1;   // 2 px-halves x 4 oc-tiles

    // stage: linear coalesced copy of the image (halo + swizzle pre-baked)
    // NOTE: producer stores slice (b,icg) at index icg*16 + b  (bug fixed vs prior round)
    {
        const char* src = (const char*)(imgH + ((size_t)(icg * 16 + b)) * 16384);
        char* dst = (char*)inH;
#pragma unroll
        for (int k = 0; k < 4; ++k) {
            frag8 v = *(const frag8*)(src + tid * 16 + k * 8192);
            *(frag8*)(dst + tid * 16 + k * 8192) = v;
        }
    }

    acc16 acc[4];
#pragma unroll
    for (int mt = 0; mt < 4; ++mt)
#pragma unroll
        for (int r = 0; r < 16; ++r) acc[mt][r] = 0.f;

    int posa[4];
#pragma unroll
    for (int mt = 0; mt < 4; ++mt) {
        int px = mtw * 128 + mt * 32 + ln;
        posa[mt] = (px < 196) ? ((px / 14) * 16 + (px % 14)) : 0;  // invalid -> halo zeros
    }

    // fragment-major weight base: + tap*262144 + c*2048
    const unsigned short* WHb = wfh + (size_t)icg * 8192 + ntw * 512 + (size_t)l * 8;
    const unsigned short* WLb = wfl + (size_t)icg * 8192 + ntw * 512 + (size_t)l * 8;

    __syncthreads();

    // 36 iterations (9 taps x 4 c), even/odd B double-buffer, barrier-free
    frag8 b0H, b0L, b1H, b1L;
    LOADB(0, b0H, b0L);
#pragma unroll
    for (int i2 = 0; i2 < 18; ++i2) {
        LOADB(i2 * 2 + 1, b1H, b1L);
        DOMFMA(i2 * 2, b0H, b0L);
        if (i2 < 17) LOADB(i2 * 2 + 2, b0H, b0L);
        DOMFMA(i2 * 2 + 1, b1H, b1L);
    }

    // epilogue: atomic partial-sum into d1 (lanes -> consecutive oc: coalesced)
    {
        const int oc = ntw * 32 + ln;
#pragma unroll
        for (int mt = 0; mt < 4; ++mt) {
#pragma unroll
            for (int r = 0; r < 16; ++r) {
                int m = (r & 3) + 8 * (r >> 2) + 4 * q;
                int px = mtw * 128 + mt * 32 + m;
                if (px < 196)
                    atomicAdd(&d1[(size_t)(b * 196 + px) * 128 + oc], acc[mt][r]);
            }
        }
    }
}

// ---------------- fused tail: conv2+conv3+tidy+NMS, one 512-thread block per batch -------
__global__ __launch_bounds__(512, 1) void k_tail(
    const float* __restrict__ d1,
    const unsigned short* __restrict__ w2h, const unsigned short* __restrict__ w2l,
    const unsigned short* __restrict__ w3h, const unsigned short* __restrict__ w3l,
    const float* __restrict__ b2, const float* __restrict__ b3,
    const float* __restrict__ wt1, const float* __restrict__ bt1,
    const float* __restrict__ wt2, const float* __restrict__ bt2,
    const float* __restrict__ wt3, const float* __restrict__ bt3,
    const int* __restrict__ anchors,
    float* __restrict__ score_out, float* __restrict__ out_idx,
    float* __restrict__ out_prob, int* __restrict__ idx_ws) {
    extern __shared__ char smem[];
    unsigned short* inH = (unsigned short*)(smem);            // [pos 304][ic 72]
    unsigned short* inL = (unsigned short*)(smem + 43776);
    unsigned short* wHs = (unsigned short*)(smem + 87552);    // [oc 128][ic 72]
    unsigned short* wLs = (unsigned short*)(smem + 105984);
    unsigned short* t1H = (unsigned short*)(smem + 124416);   // [oc16][ic 72]
    unsigned short* t1L = (unsigned short*)(smem + 126720);
    float*  d2f  = (float*)(smem + 129024);                   // [px 49][oc 128]
    float*  sbuf = (float*)(smem + 154112);                   // [1614]
    unsigned short* dhH = (unsigned short*)(smem);            // [pos 192][ic 72]
    unsigned short* dhL = (unsigned short*)(smem + 27648);
    float*  d3f  = (float*)(smem + 55296);                    // [oc 128][px 16]
    unsigned short* t2H = (unsigned short*)(smem + 63488);
    unsigned short* t2L = (unsigned short*)(smem + 65792);
    unsigned short* w3H = (unsigned short*)(smem + 68096);
    unsigned short* w3L = (unsigned short*)(smem + 86528);
    float* wt3s = (float*)(smem);
    float* y0s = (float*)(smem + 6464);
    float* x0s = (float*)(smem + 12928);
    float* y1s = (float*)(smem + 19392);
    float* x1s = (float*)(smem + 25856);
    float* ars = (float*)(smem + 32320);
    float* rv  = (float*)(smem + 38784);
    int*   ri  = (int*)(smem + 39808);

    const int tid = threadIdx.x;           // 0..511, 8 waves
    const int b = blockIdx.x;
    const int l = tid & 63, w = tid >> 6;
    const int ln = l & 31, q = l >> 5;
    const int l16 = l & 15, q4 = l >> 4;

    // ================= phase A: conv2 + t1 =================
    for (int i = tid; i < 304 * 72; i += 512) { inH[i] = 0; inL[i] = 0; }

    acc16 c2;
    acc4 t1a[2];
#pragma unroll
    for (int r = 0; r < 16; ++r) c2[r] = 0.f;
#pragma unroll
    for (int i = 0; i < 2; ++i)
#pragma unroll
        for (int r = 0; r < 4; ++r) t1a[i][r] = 0.f;

    const int mtw = w & 1, ntw = w >> 1;   // 2 px-tiles x 4 oc-tiles
    int posa2;
    {
        int px = mtw * 32 + ln;
        posa2 = (px < 49) ? ((px / 7) * 32 + (px % 7) * 2) : 256;
    }
    __syncthreads();

    for (int half = 0; half < 2; ++half) {
        const int ics = half * 64;
        for (int qq = tid; qq < 3136; qq += 512) {
            int px = qq >> 4, ic4 = (qq & 15) * 4;
            float4 v = *(const float4*)&d1[(size_t)(b * 196 + px) * 128 + ics + ic4];
            float vv[4] = {fmaxf(v.x, 0.f), fmaxf(v.y, 0.f), fmaxf(v.z, 0.f), fmaxf(v.w, 0.f)};
            ushort4 h4, l4; cvt4(vv, &h4, &l4);
            int pos = (px / 14 + 1) * 16 + (px % 14 + 1);
            *(ushort4*)&inH[pos * 72 + ic4] = h4;
            *(ushort4*)&inL[pos * 72 + ic4] = l4;
        }
        for (int qq = tid; qq < 1024; qq += 512) {
            int m = qq >> 6, k = qq & 63;
            float v = (m < 6) ? wt1[m * 128 + ics + k] : 0.f;
            unsigned short h = f2bf(v);
            t1H[m * 72 + k] = h;
            t1L[m * 72 + k] = f2bf(v - bf2f(h));
        }
        // prefetch tap-0 conv2 weights
        ushort4 pwh[4], pwl[4];
#pragma unroll
        for (int it = 0; it < 4; ++it) {
            int qq = tid + it * 512;
            int oc = qq >> 4, ic4 = (qq & 15) * 4;
            size_t gi = ((size_t)(0 * 128 + oc)) * C128 + ics + ic4;
            pwh[it] = *(const ushort4*)&w2h[gi];
            pwl[it] = *(const ushort4*)&w2l[gi];
        }
        __syncthreads();

        for (int tap = 0; tap < 9; ++tap) {
#pragma unroll
            for (int it = 0; it < 4; ++it) {
                int qq = tid + it * 512;
                int oc = qq >> 4, ic4 = (qq & 15) * 4;
                *(ushort4*)&wHs[oc * 72 + ic4] = pwh[it];
                *(ushort4*)&wLs[oc * 72 + ic4] = pwl[it];
            }
            if (tap < 8) {
#pragma unroll
                for (int it = 0; it < 4; ++it) {
                    int qq = tid + it * 512;
                    int oc = qq >> 4, ic4 = (qq & 15) * 4;
                    size_t gi = ((size_t)((tap + 1) * 128 + oc)) * C128 + ics + ic4;
                    pwh[it] = *(const ushort4*)&w2h[gi];
                    pwl[it] = *(const ushort4*)&w2l[gi];
                }
            }
            __syncthreads();
            const int off = (tap / 3) * 16 + (tap % 3);
#pragma unroll
            for (int c = 0; c < 4; ++c) {
                const int ko = c * 16 + q * 8;
                int pp = (posa2 + off) * 72 + ko;
                frag8 aH = *(const frag8*)&inH[pp];
                frag8 aL = *(const frag8*)&inL[pp];
                int oc = ntw * 32 + ln;
                frag8 bH = *(const frag8*)&wHs[oc * 72 + ko];
                frag8 bL = *(const frag8*)&wLs[oc * 72 + ko];
                c2 = __builtin_amdgcn_mfma_f32_32x32x16_bf16(aH, bH, c2, 0, 0, 0);
                c2 = __builtin_amdgcn_mfma_f32_32x32x16_bf16(aH, bL, c2, 0, 0, 0);
                c2 = __builtin_amdgcn_mfma_f32_32x32x16_bf16(aL, bH, c2, 0, 0, 0);
            }
            __syncthreads();
        }

        // t1 MFMA on this half (inH intact since last barrier)
#pragma unroll
        for (int i = 0; i < 2; ++i) {
            int px = (w * 2 + i) * 16 + l16;
            int pos = (px < 196) ? ((px / 14 + 1) * 16 + (px % 14 + 1)) : 256;
#pragma unroll
            for (int c = 0; c < 2; ++c) {
                int ko = c * 32 + q4 * 8;
                frag8 aH = *(const frag8*)&t1H[l16 * 72 + ko];
                frag8 aL = *(const frag8*)&t1L[l16 * 72 + ko];
                frag8 bH = *(const frag8*)&inH[pos * 72 + ko];
                frag8 bL = *(const frag8*)&inL[pos * 72 + ko];
                t1a[i] = __builtin_amdgcn_mfma_f32_16x16x32_bf16(aH, bH, t1a[i], 0, 0, 0);
                t1a[i] = __builtin_amdgcn_mfma_f32_16x16x32_bf16(aH, bL, t1a[i], 0, 0, 0);
                t1a[i] = __builtin_amdgcn_mfma_f32_16x16x32_bf16(aL, bH, t1a[i], 0, 0, 0);
            }
        }
        __syncthreads();
    }

    // conv2 epilogue -> d2f[px][oc]
    {
        int oc = ntw * 32 + ln;
        float bias = b2[oc];
#pragma unroll
        for (int r = 0; r < 16; ++r) {
            int m = (r & 3) + 8 * (r >> 2) + 4 * q;
            int px = mtw * 32 + m;
            if (px < 49) d2f[px * 128 + oc] = fmaxf(c2[r] + bias, 0.f);
        }
    }
    // t1 epilogue -> scores
#pragma unroll
    for (int i = 0; i < 2; ++i) {
        int px = (w * 2 + i) * 16 + l16;
#pragma unroll
        for (int r = 0; r < 4; ++r) {
            int oc = q4 * 4 + r;
            if (oc < 6 && px < 196) {
                float v = t1a[i][r] + bt1[oc];
                sbuf[oc * 196 + px] = v;
                score_out[b * NA + oc * 196 + px] = v;
            }
        }
    }
    __syncthreads();

    // ================= phase B: conv3 (waves 0-3) + t2 (waves 4-7) =================
    for (int i = tid; i < 192 * 72; i += 512) { dhH[i] = 0; dhL[i] = 0; }

    acc16 c3;
    acc4 t2a;
#pragma unroll
    for (int r = 0; r < 16; ++r) c3[r] = 0.f;
#pragma unroll
    for (int r = 0; r < 4; ++r) t2a[r] = 0.f;

    const int posb3 = (ln < 16) ? ((ln / 4) * 32 + (ln % 4) * 2) : 144;
    const int pxt2 = (w - 4) * 16 + l16;   // valid for w>=4
    const int posbt2 = (w >= 4 && pxt2 < 49) ? ((pxt2 / 7 + 1) * 16 + (pxt2 % 7 + 1)) : 144;
    __syncthreads();

    for (int half = 0; half < 2; ++half) {
        const int ics = half * 64;
        for (int qq = tid; qq < 784; qq += 512) {
            int px = qq >> 4, ic4 = (qq & 15) * 4;
            float4 v = *(const float4*)&d2f[px * 128 + ics + ic4];
            float vv[4] = {v.x, v.y, v.z, v.w};
            ushort4 h4, l4; cvt4(vv, &h4, &l4);
            int pos = (px / 7 + 1) * 16 + (px % 7 + 1);
            *(ushort4*)&dhH[pos * 72 + ic4] = h4;
            *(ushort4*)&dhL[pos * 72 + ic4] = l4;
        }
        for (int qq = tid; qq < 1024; qq += 512) {
            int m = qq >> 6, k = qq & 63;
            float v = (m < 6) ? wt2[m * 128 + ics + k] : 0.f;
            unsigned short h = f2bf(v);
            t2H[m * 72 + k] = h;
            t2L[m * 72 + k] = f2bf(v - bf2f(h));
        }
        ushort4 pwh[4], pwl[4];
#pragma unroll
        for (int it = 0; it < 4; ++it) {
            int qq = tid + it * 512;
            int oc = qq >> 4, ic4 = (qq & 15) * 4;
            size_t gi = ((size_t)(0 * 128 + oc)) * C128 + ics + ic4;
            pwh[it] = *(const ushort4*)&w3h[gi];
            pwl[it] = *(const ushort4*)&w3l[gi];
        }
        __syncthreads();

        for (int tap = 0; tap < 9; ++tap) {
#pragma unroll
            for (int it = 0; it < 4; ++it) {
                int qq = tid + it * 512;
                int oc = qq >> 4, ic4 = (qq & 15) * 4;
                *(ushort4*)&w3H[oc * 72 + ic4] = pwh[it];
                *(ushort4*)&w3L[oc * 72 + ic4] = pwl[it];
            }
            if (tap < 8) {
#pragma unroll
                for (int it = 0; it < 4; ++it) {
                    int qq = tid + it * 512;
                    int oc = qq >> 4, ic4 = (qq & 15) * 4;
                    size_t gi = ((size_t)((tap + 1) * 128 + oc)) * C128 + ics + ic4;
                    pwh[it] = *(const ushort4*)&w3h[gi];
                    pwl[it] = *(const ushort4*)&w3l[gi];
                }
            }
            __syncthreads();
            const int off = (tap / 3) * 16 + (tap % 3);
            if (w < 4) {
#pragma unroll
                for (int c = 0; c < 4; ++c) {
                    const int ko = c * 16 + q * 8;
                    int pp = (posb3 + off) * 72 + ko;
                    frag8 aH = *(const frag8*)&dhH[pp];
                    frag8 aL = *(const frag8*)&dhL[pp];
                    int oc = w * 32 + ln;
                    frag8 bH = *(const frag8*)&w3H[oc * 72 + ko];
                    frag8 bL = *(const frag8*)&w3L[oc * 72 + ko];
                    c3 = __builtin_amdgcn_mfma_f32_32x32x16_bf16(aH, bH, c3, 0, 0, 0);
                    c3 = __builtin_amdgcn_mfma_f32_32x32x16_bf16(aH, bL, c3, 0, 0, 0);
                    c3 = __builtin_amdgcn_mfma_f32_32x32x16_bf16(aL, bH, c3, 0, 0, 0);
                }
            } else if (tap == 0) {
                // t2 on this half (dh is stable during the tap loop)
#pragma unroll
                for (int c = 0; c < 2; ++c) {
                    int ko = c * 32 + q4 * 8;
                    frag8 aH = *(const frag8*)&t2H[l16 * 72 + ko];
                    frag8 aL = *(const frag8*)&t2L[l16 * 72 + ko];
                    frag8 bH = *(const frag8*)&dhH[posbt2 * 72 + ko];
                    frag8 bL = *(const frag8*)&dhL[posbt2 * 72 + ko];
                    t2a = __builtin_amdgcn_mfma_f32_16x16x32_bf16(aH, bH, t2a, 0, 0, 0);
                    t2a = __builtin_amdgcn_mfma_f32_16x16x32_bf16(aH, bL, t2a, 0, 0, 0);
                    t2a = __builtin_amdgcn_mfma_f32_16x16x32_bf16(aL, bH, t2a, 0, 0, 0);
                }
            }
            __syncthreads();
        }
    }

    // conv3 epilogue -> d3f[oc][px]
    if (w < 4) {
        int oc = w * 32 + ln;
        float bias = b3[oc];
#pragma unroll
        for (int r = 0; r < 16; ++r) {
            int px = (r & 3) + 8 * (r >> 2) + 4 * q;
            if (px < 16) d3f[oc * 16 + px] = fmaxf(c3[r] + bias, 0.f);
        }
    } else {
        // t2 epilogue -> scores
#pragma unroll
        for (int r = 0; r < 4; ++r) {
            int oc = q4 * 4 + r;
            if (oc < 6 && pxt2 < 49) {
                float v = t2a[r] + bt2[oc];
                sbuf[1176 + oc * 49 + pxt2] = v;
                score_out[b * NA + 1176 + oc * 49 + pxt2] = v;
            }
        }
    }
    for (int i = tid; i < 1152; i += 512) wt3s[i] = wt3[i];
    __syncthreads();

    // ================= phase C: t3 (VALU) + anchor staging =================
    if (tid < 144) {
        int oc = tid >> 4, px = tid & 15;
        float s = bt3[oc];
        for (int ic = 0; ic < 128; ++ic) s += wt3s[oc * 128 + ic] * d3f[ic * 16 + px];
        sbuf[1470 + oc * 16 + px] = s;
        score_out[b * NA + 1470 + oc * 16 + px] = s;
    }
    for (int j = tid; j < NA; j += 512) {
        int4 a = ((const int4*)anchors)[j];
        float a0 = (float)a.x, a1 = (float)a.y, a2 = (float)a.z, a3 = (float)a.w;
        y0s[j] = a0; x0s[j] = a1; y1s[j] = a2; x1s[j] = a3;
        ars[j] = (a2 - a0) * (a3 - a1);
    }
    __syncthreads();

    // ================= phase D: greedy hard-NMS top-4 (shuffle reduce) =================
    for (int it = 0; it < TOPN; ++it) {
        float bv = -INFINITY; int bi = NA;
        for (int j = tid; j < NA; j += 512) {
            float v = sbuf[j];
            if (v > bv || (v == bv && j < bi)) { bv = v; bi = j; }
        }
#pragma unroll
        for (int d = 1; d < 64; d <<= 1) {
            float ov = __shfl_xor(bv, d, 64);
            int   oi = __shfl_xor(bi, d, 64);
            if (ov > bv || (ov == bv && oi < bi)) { bv = ov; bi = oi; }
        }
        if (l == 0) { rv[w] = bv; ri[w] = bi; }
        __syncthreads();
        if (tid == 0) {
            float V = rv[0]; int K = ri[0];
#pragma unroll
            for (int j = 1; j < 8; ++j) {
                float ov = rv[j]; int oi = ri[j];
                if (ov > V || (ov == V && oi < K)) { V = ov; K = oi; }
            }
            ri[8] = K;
            out_idx[b * TOPN + it] = (float)K;
            out_prob[b * TOPN + it] = V;
            idx_ws[b * TOPN + it] = K;
        }
        __syncthreads();
        int K = ri[8];
        float ky0 = y0s[K], kx0 = x0s[K], ky1 = y1s[K], kx1 = x1s[K], ka = ars[K];
        for (int j = tid; j < NA; j += 512) {
            float iy = fmaxf(fminf(y1s[j], ky1) - fmaxf(y0s[j], ky0), 0.f);
            float ix = fmaxf(fminf(x1s[j], kx1) - fmaxf(x0s[j], kx0), 0.f);
            float inter = iy * ix;
            float iou = inter / (ars[j] + ka - inter);
            if (iou >= 0.25f) sbuf[j] = -INFINITY;
        }
        __syncthreads();
    }
}

// ---------------- bilinear crop-resize ----------------
__global__ __launch_bounds__(256) void k_crop(const float* __restrict__ x,
                                              const int* __restrict__ anchors,
                                              const int* __restrict__ idx_ws,
                                              float* __restrict__ out) {
    int blk = blockIdx.x;
    int crop = blk / OUTS;
    int i = blk % OUTS;
    int j = threadIdx.x;
    if (j >= OUTS) return;
    int b = crop >> 2;
    int a = idx_ws[crop];
    int y0 = anchors[a * 4], x0 = anchors[a * 4 + 1];
    int y1 = anchors[a * 4 + 2], x1 = anchors[a * 4 + 3];

    float ti = (float)i / 223.f;
    float ys = (float)y0 + ti * (float)(y1 - y0 - 1);
    int yi0 = (int)ys;
    int yi1 = min(yi0 + 1, HP - 1);
    float wy = ys - (float)yi0;

    float tj = (float)j / 223.f;
    float xs = (float)x0 + tj * (float)(x1 - x0 - 1);
    int xi0 = (int)xs;
    int xi1 = min(xi0 + 1, HP - 1);
    float wx = xs - (float)xi0;

    int ry0 = yi0 - PADW, ry1 = yi1 - PADW, rx0 = xi0 - PADW, rx1 = xi1 - PADW;
    bool vy0 = (ry0 >= 0) && (ry0 < IM), vy1 = (ry1 >= 0) && (ry1 < IM);
    bool vx0 = (rx0 >= 0) && (rx0 < IM), vx1 = (rx1 >= 0) && (rx1 < IM);

    float w00 = (1.f - wy) * (1.f - wx), w01 = (1.f - wy) * wx;
    float w10 = wy * (1.f - wx), w11 = wy * wx;

#pragma unroll
    for (int c = 0; c < 3; ++c) {
        const float* xp = x + (size_t)(b * 3 + c) * IM * IM;
        float g00 = (vy0 && vx0) ? xp[ry0 * IM + rx0] : 0.f;
        float g01 = (vy0 && vx1) ? xp[ry0 * IM + rx1] : 0.f;
        float g10 = (vy1 && vx0) ? xp[ry1 * IM + rx0] : 0.f;
        float g11 = (vy1 && vx1) ? xp[ry1 * IM + rx1] : 0.f;
        out[(size_t)(crop * 3 + c) * OUTS * OUTS + i * OUTS + j] =
            g00 * w00 + g01 * w01 + g10 * w10 + g11 * w11;
    }
}

extern "C" void kernel_launch(void* const* d_in, const int* in_sizes, int n_in,
                              void* d_out, int out_size, void* d_ws, size_t ws_size,
                              hipStream_t stream) {
    (void)in_sizes; (void)n_in; (void)out_size; (void)ws_size;
    const float* x    = (const float*)d_in[0];
    const float* rpn  = (const float*)d_in[1];
    const float* w1   = (const float*)d_in[2];
    const float* b1   = (const float*)d_in[3];
    const float* w2   = (const float*)d_in[4];
    const float* b2   = (const float*)d_in[5];
    const float* w3   = (const float*)d_in[6];
    const float* b3   = (const float*)d_in[7];
    const float* wt1  = (const float*)d_in[8];
    const float* bt1  = (const float*)d_in[9];
    const float* wt2  = (const float*)d_in[10];
    const float* bt2  = (const float*)d_in[11];
    const float* wt3  = (const float*)d_in[12];
    const float* bt3  = (const float*)d_in[13];
    const int*   anc  = (const int*)d_in[14];

    float* out = (float*)d_out;
    float* ws  = (float*)d_ws;
    float* d1  = ws + WS_D1;
    int*   idxw = (int*)(ws + WS_IDX);
    unsigned short* w1h = (unsigned short*)(ws + WS_WT);
    unsigned short* w1l = w1h + NWT1;
    unsigned short* w2h = w1l + NWT1;
    unsigned short* w2l = w2h + NWT2;
    unsigned short* w3h = w2l + NWT2;
    unsigned short* w3l = w3h + NWT2;
    unsigned short* imgH = w3l + NWT2;   // NIMG ushorts

    static const int TAIL_LDS = 160568;
    hipFuncSetAttribute((const void*)k_tail, hipFuncAttributeMaxDynamicSharedMemorySize, TAIL_LDS);

    k_prep<<<1160, 256, 0, stream>>>(w1, w1h, w1l, w2, w2h, w2l, w3, w3h, w3l,
                                     rpn, imgH, b1, d1);
    k_conv1_mfma<<<512, 512, 0, stream>>>(imgH, w1h, w1l, d1);
    k_tail<<<BATCH, 512, TAIL_LDS, stream>>>(d1, w2h, w2l, w3h, w3l, b2, b3,
                                             wt1, bt1, wt2, bt2, wt3, bt3, anc,
                                             out + OFF_SCORE, out + OFF_TOPIDX,
                                             out + OFF_TOPPROB, idxw);
    k_crop<<<BATCH * TOPN * OUTS, 256, 0, stream>>>(x, anc, idxw, out);
}

// Round 7
// 272.314 us; speedup vs baseline: 1.0719x; 1.0058x over previous
//
#include <hip/hip_runtime.h>
#include <math.h>

#define BATCH 16
#define TOPN 4
#define OUTS 224
#define PADW 224
#define IM 448
#define HP 896
#define NA 1614
#define IC1 2048
#define C128 128

// d_out float offsets
#define N_PART (BATCH*TOPN*3*OUTS*OUTS)       // 9,633,792
#define OFF_TOPIDX  (N_PART)
#define OFF_TOPPROB (N_PART + BATCH*TOPN)
#define OFF_SCORE   (N_PART + 2*BATCH*TOPN)

// ws float offsets.  d1 is [b][px 196][oc 128]
#define WS_D1 0
#define WS_IDX (BATCH*C128*196)                // 64 ints
#define WS_WT  (WS_IDX + 64)                   // repacked weights (ushort)
#define NWT1 (9*2048*128)
#define NWT2 (9*128*128)
#define NIMG (16*32*16384)                     // pre-swizzled conv1 input images (ushort)

typedef __attribute__((ext_vector_type(8))) short frag8;     // 8 bf16 (4 VGPRs)
typedef __attribute__((ext_vector_type(16))) float acc16;    // 16 fp32 acc (32x32)
typedef __attribute__((ext_vector_type(4)))  float acc4;     // 4 fp32 acc (16x16)

__device__ __forceinline__ unsigned short f2bf(float f) {
    unsigned int u = __float_as_uint(f);
    u = (u + 0x7fffu + ((u >> 16) & 1u)) >> 16;   // RNE
    return (unsigned short)u;
}
__device__ __forceinline__ float bf2f(unsigned short h) {
    return __uint_as_float(((unsigned int)h) << 16);
}
__device__ __forceinline__ void cvt4(const float* v, ushort4* h, ushort4* lo) {
    unsigned short hh[4], ll[4];
#pragma unroll
    for (int e = 0; e < 4; ++e) { hh[e] = f2bf(v[e]); ll[e] = f2bf(v[e] - bf2f(hh[e])); }
    *h  = make_ushort4(hh[0], hh[1], hh[2], hh[3]);
    *lo = make_ushort4(ll[0], ll[1], ll[2], ll[3]);
}

// ---------------- fused prep ----------------
// w1 fragment-major repack, one (oc, 8-ic) pair per thread, all 9 taps.
// dst element = t*262144 + kg*16384 + h*8192 + c*2048 + ot*512 + l*8
//   with oc = ot*32 + (l&31), ic = kg*128 + h*64 + c*16 + (l>>5)*8 + e
__device__ __forceinline__ void w1frag_body(const float* __restrict__ w1,
                                            unsigned short* __restrict__ w1h,
                                            unsigned short* __restrict__ w1l,
                                            int i) {
    if (i >= 32768) return;
    int oc5 = i & 31;
    int q8  = (i >> 5) & 1;
    int ot  = (i >> 6) & 3;
    int c   = (i >> 8) & 3;
    int h   = (i >> 10) & 1;
    int kg  = (i >> 11) & 15;
    int oc  = ot * 32 + oc5;
    int ic0 = kg * 128 + h * 64 + c * 16 + q8 * 8;
    int l   = q8 * 32 + oc5;
    const float* src = w1 + ((size_t)oc * IC1 + ic0) * 9;
    size_t dbase = (size_t)kg * 16384 + h * 8192 + c * 2048 + ot * 512 + l * 8;
#pragma unroll
    for (int t = 0; t < 9; ++t) {
        frag8 hv, lv;
#pragma unroll
        for (int e = 0; e < 8; ++e) {
            float v = src[e * 9 + t];
            unsigned short hs = f2bf(v);
            hv[e] = (short)hs;
            lv[e] = (short)f2bf(v - bf2f(hs));
        }
        size_t dst = dbase + (size_t)t * 262144;
        *(frag8*)&w1h[dst] = hv;
        *(frag8*)&w1l[dst] = lv;
    }
}

// 128x128x3x3 fragment-major repack (w2, w3): dst = t*16384 + h*8192 + c*2048 + ot*512 + l*8
//   oc = ot*32 + (l&31), ic = h*64 + c*16 + (l>>5)*8 + e
__device__ __forceinline__ void wfrag128_body(const float* __restrict__ w,
                                              unsigned short* __restrict__ wh,
                                              unsigned short* __restrict__ wl,
                                              int i) {
    if (i >= 16384) return;
    int oc5 = i & 31;
    int q8  = (i >> 5) & 1;
    int ot  = (i >> 6) & 3;
    int c   = (i >> 8) & 3;
    int h   = (i >> 10) & 1;
    int oc  = ot * 32 + oc5;
    int ic0 = h * 64 + c * 16 + q8 * 8;
    int l   = q8 * 32 + oc5;
    const float* src = w + ((size_t)oc * C128 + ic0) * 9;
    size_t dbase = (size_t)h * 8192 + c * 2048 + ot * 512 + l * 8;
#pragma unroll
    for (int t = 0; t < 9; ++t) {
        frag8 hv, lv;
#pragma unroll
        for (int e = 0; e < 8; ++e) {
            float v = src[e * 9 + t];
            unsigned short hs = f2bf(v);
            hv[e] = (short)hs;
            lv[e] = (short)f2bf(v - bf2f(hs));
        }
        size_t dst = dbase + (size_t)t * 16384;
        *(frag8*)&wh[dst] = hv;
        *(frag8*)&wl[dst] = lv;
    }
}

// grid 1160: [0,128) w1frag | [128,192) w2frag | [192,256) w3frag | [256,768) img | [768,1160) init_d1
__global__ __launch_bounds__(256) void k_prep(
    const float* __restrict__ w1, unsigned short* __restrict__ w1h, unsigned short* __restrict__ w1l,
    const float* __restrict__ w2, unsigned short* __restrict__ w2fh, unsigned short* __restrict__ w2fl,
    const float* __restrict__ w3, unsigned short* __restrict__ w3fh, unsigned short* __restrict__ w3fl,
    const float* __restrict__ rpn, unsigned short* __restrict__ imgH,
    const float* __restrict__ b1, float* __restrict__ d1) {
    __shared__ float tile[64 * 201];
    const int tid = threadIdx.x;
    const int blk = blockIdx.x;
    if (blk < 128) {
        w1frag_body(w1, w1h, w1l, blk * 256 + tid);
    } else if (blk < 192) {
        wfrag128_body(w2, w2fh, w2fl, (blk - 128) * 256 + tid);
    } else if (blk < 256) {
        wfrag128_body(w3, w3fh, w3fl, (blk - 192) * 256 + tid);
    } else if (blk < 768) {
        // build pre-swizzled 32KB image for slice (b, icg): [256 pos][64 ic] bf16-hi
        const int bb = blk - 256;
        const int b = bb & 15, icg = bb >> 4;
        const int ic0 = icg * 64;
        char* img = (char*)(imgH + (size_t)bb * 16384);   // slice index = icg*16 + b
        for (int qq = tid; qq < 3136; qq += 256) {
            int icl = qq / 49, r = qq % 49, p = r * 4;
            const float4 v = *(const float4*)&rpn[(size_t)(b * IC1 + ic0 + icl) * 196 + p];
            tile[icl * 201 + p + 0] = v.x;
            tile[icl * 201 + p + 1] = v.y;
            tile[icl * 201 + p + 2] = v.z;
            tile[icl * 201 + p + 3] = v.w;
        }
        __syncthreads();
        // data cells: pos = (px/14+1)*16 + (px%14+1), XOR-swizzled byte layout
        for (int qq = tid; qq < 3136; qq += 256) {
            int px = qq >> 4, ic4 = (qq & 15) * 4;
            float vv[4];
            unsigned short hh[4];
#pragma unroll
            for (int e = 0; e < 4; ++e) { vv[e] = tile[(ic4 + e) * 201 + px]; hh[e] = f2bf(vv[e]); }
            int pos = (px / 14 + 1) * 16 + (px % 14 + 1);
            int byo = (pos * 128 + ic4 * 2) ^ ((pos & 7) << 4);
            *(ushort4*)(img + byo) = make_ushort4(hh[0], hh[1], hh[2], hh[3]);
        }
        // halo cells: 60 positions, zero full 128B rows (swizzle-invariant)
        for (int qq = tid; qq < 960; qq += 256) {
            int hp = qq >> 4, sub = qq & 15;
            int pos;
            if (hp < 16)      pos = hp;                       // row 0
            else if (hp < 32) pos = 240 + (hp - 16);          // row 15
            else if (hp < 46) pos = (hp - 31) * 16;           // col 0, rows 1..14
            else              pos = (hp - 45) * 16 + 15;      // col 15, rows 1..14
            *(ushort4*)(img + pos * 128 + sub * 8) = make_ushort4(0, 0, 0, 0);
        }
    } else {
        int i = (blk - 768) * 256 + tid;     // one float4 per thread, 392 blocks exactly
        int base = i * 4;
        float4 v;
        v.x = b1[(base + 0) & 127]; v.y = b1[(base + 1) & 127];
        v.z = b1[(base + 2) & 127]; v.w = b1[(base + 3) & 127];
        *(float4*)&d1[base] = v;
    }
}

// ---------------- conv1 via MFMA 32x32x16 bf16, 2-term (input bf16, weight hi+lo) -------
// Grid 512: blk = b*32 + icg  (XCD = icg%8 -> per-XCD weight set 4 slices = 1.2MB, L2-hot)
// Wave tile 128px x 32oc; per iter: 4 A-ds + 2 B-vmem + 8 MFMA; 3-deep B ring to hide L2 lat.

#define LOADB(it, BH, BL) { \
    const int o_ = ((it) >> 2) * 262144 + ((it) & 3) * 2048; \
    BH = *(const frag8*)&WHb[o_]; BL = *(const frag8*)&WLb[o_]; }

#define DOMFMA(it, BH, BL) { \
    const int tap_ = (it) >> 2; \
    const int off_ = (tap_ / 3) * 16 + (tap_ % 3); \
    const int kb_ = ((it) & 3) * 32 + q * 16; \
    frag8 aH[4]; \
    _Pragma("unroll") \
    for (int mt_ = 0; mt_ < 4; ++mt_) { \
        const int p_ = posa[mt_] + off_; \
        const int by_ = (p_ * 128 + kb_) ^ ((p_ & 7) << 4); \
        aH[mt_] = *(const frag8*)((const char*)inH + by_); \
    } \
    _Pragma("unroll") \
    for (int mt_ = 0; mt_ < 4; ++mt_) { \
        acc[mt_] = __builtin_amdgcn_mfma_f32_32x32x16_bf16(aH[mt_], BH, acc[mt_], 0, 0, 0); \
        acc[mt_] = __builtin_amdgcn_mfma_f32_32x32x16_bf16(aH[mt_], BL, acc[mt_], 0, 0, 0); \
    } }

__global__ __launch_bounds__(512, 4) void k_conv1_mfma(const unsigned short* __restrict__ imgH,
                                                       const unsigned short* __restrict__ wfh,
                                                       const unsigned short* __restrict__ wfl,
                                                       float* __restrict__ d1) {
    __shared__ unsigned short inH[256 * 64];   // 32KB pre-swizzled [pos][ic64] bf16-hi

    const int tid = threadIdx.x;
    const int blk = blockIdx.x;
    const int b = blk >> 5;
    const int icg = blk & 31;
    const int l = tid & 63, w = tid >> 6;
    const int ln = l & 31, q = l >> 5;
    const int mtw = w & 1, ntw = w >> 1;   // 2 px-halves x 4 oc-tiles

    // stage: linear coalesced copy of the image (halo + swizzle pre-baked); slice = icg*16+b
    {
        const char* src = (const char*)(imgH + ((size_t)(icg * 16 + b)) * 16384);
        char* dst = (char*)inH;
#pragma unroll
        for (int k = 0; k < 4; ++k) {
            frag8 v = *(const frag8*)(src + tid * 16 + k * 8192);
            *(frag8*)(dst + tid * 16 + k * 8192) = v;
        }
    }

    acc16 acc[4];
#pragma unroll
    for (int mt = 0; mt < 4; ++mt)
#pragma unroll
        for (int r = 0; r < 16; ++r) acc[mt][r] = 0.f;

    int posa[4];
#pragma unroll
    for (int mt = 0; mt < 4; ++mt) {
        int px = mtw * 128 + mt * 32 + ln;
        posa[mt] = (px < 196) ? ((px / 14) * 16 + (px % 14)) : 0;  // invalid -> halo zeros
    }

    // fragment-major weight base: + tap*262144 + c*2048
    const unsigned short* WHb = wfh + (size_t)icg * 8192 + ntw * 512 + (size_t)l * 8;
    const unsigned short* WLb = wfl + (size_t)icg * 8192 + ntw * 512 + (size_t)l * 8;

    __syncthreads();

    // 36 iterations (9 taps x 4 c), 3-deep B ring, barrier-free
    frag8 B0H, B0L, B1H, B1L, B2H, B2L;
    LOADB(0, B0H, B0L);
    LOADB(1, B1H, B1L);
    LOADB(2, B2H, B2L);
#pragma unroll
    for (int g = 0; g < 12; ++g) {
        DOMFMA(g * 3 + 0, B0H, B0L); if (g < 11) LOADB(g * 3 + 3, B0H, B0L);
        DOMFMA(g * 3 + 1, B1H, B1L); if (g < 11) LOADB(g * 3 + 4, B1H, B1L);
        DOMFMA(g * 3 + 2, B2H, B2L); if (g < 11) LOADB(g * 3 + 5, B2H, B2L);
    }

    // epilogue: atomic partial-sum into d1 (lanes -> consecutive oc: coalesced)
    {
        const int oc = ntw * 32 + ln;
#pragma unroll
        for (int mt = 0; mt < 4; ++mt) {
#pragma unroll
            for (int r = 0; r < 16; ++r) {
                int m = (r & 3) + 8 * (r >> 2) + 4 * q;
                int px = mtw * 128 + mt * 32 + m;
                if (px < 196)
                    atomicAdd(&d1[(size_t)(b * 196 + px) * 128 + oc], acc[mt][r]);
            }
        }
    }
}

// ---------------- fused tail: conv2+conv3+tidy+NMS, one 512-thread block per batch -------
// conv2/conv3 B-operands reg-direct from L2 (frag-major), 4-deep ring, barrier-free inner loops.

#define LOADB2(it, BH, BL) { \
    const int o_ = ((it) >> 2) * 16384 + ((it) & 3) * 2048; \
    BH = *(const frag8*)&W2H[o_]; BL = *(const frag8*)&W2L[o_]; }

#define DOC2(it, BH, BL) { \
    const int tap_ = (it) >> 2; \
    const int off_ = (tap_ / 3) * 16 + (tap_ % 3); \
    const int ko_ = ((it) & 3) * 16 + q * 8; \
    const int pp_ = (posa2 + off_) * 72 + ko_; \
    frag8 aH = *(const frag8*)&inH[pp_]; \
    frag8 aL = *(const frag8*)&inL[pp_]; \
    c2 = __builtin_amdgcn_mfma_f32_32x32x16_bf16(aH, BH, c2, 0, 0, 0); \
    c2 = __builtin_amdgcn_mfma_f32_32x32x16_bf16(aH, BL, c2, 0, 0, 0); \
    c2 = __builtin_amdgcn_mfma_f32_32x32x16_bf16(aL, BH, c2, 0, 0, 0); }

#define LOADB3(it, BH, BL) { \
    const int o_ = ((it) >> 2) * 16384 + ((it) & 3) * 2048; \
    BH = *(const frag8*)&W3Hp[o_]; BL = *(const frag8*)&W3Lp[o_]; }

#define DOC3(it, BH, BL) { \
    const int tap_ = (it) >> 2; \
    const int off_ = (tap_ / 3) * 16 + (tap_ % 3); \
    const int ko_ = ((it) & 3) * 16 + q * 8; \
    const int pp_ = (posb3 + off_) * 72 + ko_; \
    frag8 aH = *(const frag8*)&dhH[pp_]; \
    frag8 aL = *(const frag8*)&dhL[pp_]; \
    c3 = __builtin_amdgcn_mfma_f32_32x32x16_bf16(aH, BH, c3, 0, 0, 0); \
    c3 = __builtin_amdgcn_mfma_f32_32x32x16_bf16(aH, BL, c3, 0, 0, 0); \
    c3 = __builtin_amdgcn_mfma_f32_32x32x16_bf16(aL, BH, c3, 0, 0, 0); }

__global__ __launch_bounds__(512, 1) void k_tail(
    const float* __restrict__ d1,
    const unsigned short* __restrict__ w2fh, const unsigned short* __restrict__ w2fl,
    const unsigned short* __restrict__ w3fh, const unsigned short* __restrict__ w3fl,
    const float* __restrict__ b2, const float* __restrict__ b3,
    const float* __restrict__ wt1, const float* __restrict__ bt1,
    const float* __restrict__ wt2, const float* __restrict__ bt2,
    const float* __restrict__ wt3, const float* __restrict__ bt3,
    const int* __restrict__ anchors,
    float* __restrict__ score_out, float* __restrict__ out_idx,
    float* __restrict__ out_prob, int* __restrict__ idx_ws) {
    extern __shared__ char smem[];
    unsigned short* inH = (unsigned short*)(smem);            // [pos 304][ic 72]
    unsigned short* inL = (unsigned short*)(smem + 43776);
    unsigned short* t1H = (unsigned short*)(smem + 124416);   // [oc16][ic 72]
    unsigned short* t1L = (unsigned short*)(smem + 126720);
    float*  d2f  = (float*)(smem + 129024);                   // [px 49][oc 128]
    float*  sbuf = (float*)(smem + 154112);                   // [1614]
    unsigned short* dhH = (unsigned short*)(smem);            // [pos 192][ic 72]
    unsigned short* dhL = (unsigned short*)(smem + 27648);
    float*  d3f  = (float*)(smem + 55296);                    // [oc 128][px 16]
    unsigned short* t2H = (unsigned short*)(smem + 63488);
    unsigned short* t2L = (unsigned short*)(smem + 65792);
    float* wt3s = (float*)(smem);
    float* y0s = (float*)(smem + 6464);
    float* x0s = (float*)(smem + 12928);
    float* y1s = (float*)(smem + 19392);
    float* x1s = (float*)(smem + 25856);
    float* ars = (float*)(smem + 32320);
    float* rv  = (float*)(smem + 38784);
    int*   ri  = (int*)(smem + 39808);

    const int tid = threadIdx.x;           // 0..511, 8 waves
    const int b = blockIdx.x;
    const int l = tid & 63, w = tid >> 6;
    const int ln = l & 31, q = l >> 5;
    const int l16 = l & 15, q4 = l >> 4;

    // ================= phase A: conv2 + t1 =================
    for (int i = tid; i < 304 * 72; i += 512) { inH[i] = 0; inL[i] = 0; }

    acc16 c2;
    acc4 t1a[2];
#pragma unroll
    for (int r = 0; r < 16; ++r) c2[r] = 0.f;
#pragma unroll
    for (int i = 0; i < 2; ++i)
#pragma unroll
        for (int r = 0; r < 4; ++r) t1a[i][r] = 0.f;

    const int mtw = w & 1, ntw = w >> 1;   // 2 px-tiles x 4 oc-tiles
    int posa2;
    {
        int px = mtw * 32 + ln;
        posa2 = (px < 49) ? ((px / 7) * 32 + (px % 7) * 2) : 256;
    }
    __syncthreads();

    for (int half = 0; half < 2; ++half) {
        const int ics = half * 64;
        for (int qq = tid; qq < 3136; qq += 512) {
            int px = qq >> 4, ic4 = (qq & 15) * 4;
            float4 v = *(const float4*)&d1[(size_t)(b * 196 + px) * 128 + ics + ic4];
            float vv[4] = {fmaxf(v.x, 0.f), fmaxf(v.y, 0.f), fmaxf(v.z, 0.f), fmaxf(v.w, 0.f)};
            ushort4 h4, l4; cvt4(vv, &h4, &l4);
            int pos = (px / 14 + 1) * 16 + (px % 14 + 1);
            *(ushort4*)&inH[pos * 72 + ic4] = h4;
            *(ushort4*)&inL[pos * 72 + ic4] = l4;
        }
        for (int qq = tid; qq < 1024; qq += 512) {
            int m = qq >> 6, k = qq & 63;
            float v = (m < 6) ? wt1[m * 128 + ics + k] : 0.f;
            unsigned short h = f2bf(v);
            t1H[m * 72 + k] = h;
            t1L[m * 72 + k] = f2bf(v - bf2f(h));
        }
        __syncthreads();

        // barrier-free conv2: 36 iters (9 taps x 4 c), 4-deep B ring from L2
        {
            const unsigned short* W2H = w2fh + half * 8192 + ntw * 512 + (size_t)l * 8;
            const unsigned short* W2L = w2fl + half * 8192 + ntw * 512 + (size_t)l * 8;
            frag8 B0H, B0L, B1H, B1L, B2H, B2L, B3H, B3L;
            LOADB2(0, B0H, B0L);
            LOADB2(1, B1H, B1L);
            LOADB2(2, B2H, B2L);
            LOADB2(3, B3H, B3L);
#pragma unroll
            for (int g = 0; g < 9; ++g) {
                DOC2(g * 4 + 0, B0H, B0L); if (g < 8) LOADB2(g * 4 + 4, B0H, B0L);
                DOC2(g * 4 + 1, B1H, B1L); if (g < 8) LOADB2(g * 4 + 5, B1H, B1L);
                DOC2(g * 4 + 2, B2H, B2L); if (g < 8) LOADB2(g * 4 + 6, B2H, B2L);
                DOC2(g * 4 + 3, B3H, B3L); if (g < 8) LOADB2(g * 4 + 7, B3H, B3L);
            }
        }

        // t1 MFMA on this half (inH intact; no one wrote LDS since stage barrier)
#pragma unroll
        for (int i = 0; i < 2; ++i) {
            int px = (w * 2 + i) * 16 + l16;
            int pos = (px < 196) ? ((px / 14 + 1) * 16 + (px % 14 + 1)) : 256;
#pragma unroll
            for (int c = 0; c < 2; ++c) {
                int ko = c * 32 + q4 * 8;
                frag8 aH = *(const frag8*)&t1H[l16 * 72 + ko];
                frag8 aL = *(const frag8*)&t1L[l16 * 72 + ko];
                frag8 bH = *(const frag8*)&inH[pos * 72 + ko];
                frag8 bL = *(const frag8*)&inL[pos * 72 + ko];
                t1a[i] = __builtin_amdgcn_mfma_f32_16x16x32_bf16(aH, bH, t1a[i], 0, 0, 0);
                t1a[i] = __builtin_amdgcn_mfma_f32_16x16x32_bf16(aH, bL, t1a[i], 0, 0, 0);
                t1a[i] = __builtin_amdgcn_mfma_f32_16x16x32_bf16(aL, bH, t1a[i], 0, 0, 0);
            }
        }
        __syncthreads();
    }

    // conv2 epilogue -> d2f[px][oc]
    {
        int oc = ntw * 32 + ln;
        float bias = b2[oc];
#pragma unroll
        for (int r = 0; r < 16; ++r) {
            int m = (r & 3) + 8 * (r >> 2) + 4 * q;
            int px = mtw * 32 + m;
            if (px < 49) d2f[px * 128 + oc] = fmaxf(c2[r] + bias, 0.f);
        }
    }
    // t1 epilogue -> scores
#pragma unroll
    for (int i = 0; i < 2; ++i) {
        int px = (w * 2 + i) * 16 + l16;
#pragma unroll
        for (int r = 0; r < 4; ++r) {
            int oc = q4 * 4 + r;
            if (oc < 6 && px < 196) {
                float v = t1a[i][r] + bt1[oc];
                sbuf[oc * 196 + px] = v;
                score_out[b * NA + oc * 196 + px] = v;
            }
        }
    }
    __syncthreads();

    // ================= phase B: conv3 (waves 0-3) + t2 (waves 4-7) =================
    for (int i = tid; i < 192 * 72; i += 512) { dhH[i] = 0; dhL[i] = 0; }

    acc16 c3;
    acc4 t2a;
#pragma unroll
    for (int r = 0; r < 16; ++r) c3[r] = 0.f;
#pragma unroll
    for (int r = 0; r < 4; ++r) t2a[r] = 0.f;

    const int posb3 = (ln < 16) ? ((ln / 4) * 32 + (ln % 4) * 2) : 144;
    const int pxt2 = (w - 4) * 16 + l16;   // valid for w>=4
    const int posbt2 = (w >= 4 && pxt2 < 49) ? ((pxt2 / 7 + 1) * 16 + (pxt2 % 7 + 1)) : 144;
    __syncthreads();

    for (int half = 0; half < 2; ++half) {
        const int ics = half * 64;
        for (int qq = tid; qq < 784; qq += 512) {
            int px = qq >> 4, ic4 = (qq & 15) * 4;
            float4 v = *(const float4*)&d2f[px * 128 + ics + ic4];
            float vv[4] = {v.x, v.y, v.z, v.w};
            ushort4 h4, l4; cvt4(vv, &h4, &l4);
            int pos = (px / 7 + 1) * 16 + (px % 7 + 1);
            *(ushort4*)&dhH[pos * 72 + ic4] = h4;
            *(ushort4*)&dhL[pos * 72 + ic4] = l4;
        }
        for (int qq = tid; qq < 1024; qq += 512) {
            int m = qq >> 6, k = qq & 63;
            float v = (m < 6) ? wt2[m * 128 + ics + k] : 0.f;
            unsigned short h = f2bf(v);
            t2H[m * 72 + k] = h;
            t2L[m * 72 + k] = f2bf(v - bf2f(h));
        }
        __syncthreads();

        if (w < 4) {
            // barrier-free conv3: 36 iters, 4-deep B ring; ot = w
            const unsigned short* W3Hp = w3fh + half * 8192 + w * 512 + (size_t)l * 8;
            const unsigned short* W3Lp = w3fl + half * 8192 + w * 512 + (size_t)l * 8;
            frag8 B0H, B0L, B1H, B1L, B2H, B2L, B3H, B3L;
            LOADB3(0, B0H, B0L);
            LOADB3(1, B1H, B1L);
            LOADB3(2, B2H, B2L);
            LOADB3(3, B3H, B3L);
#pragma unroll
            for (int g = 0; g < 9; ++g) {
                DOC3(g * 4 + 0, B0H, B0L); if (g < 8) LOADB3(g * 4 + 4, B0H, B0L);
                DOC3(g * 4 + 1, B1H, B1L); if (g < 8) LOADB3(g * 4 + 5, B1H, B1L);
                DOC3(g * 4 + 2, B2H, B2L); if (g < 8) LOADB3(g * 4 + 6, B2H, B2L);
                DOC3(g * 4 + 3, B3H, B3L); if (g < 8) LOADB3(g * 4 + 7, B3H, B3L);
            }
        } else {
            // t2 on this half (dh stable until end-of-half barrier)
#pragma unroll
            for (int c = 0; c < 2; ++c) {
                int ko = c * 32 + q4 * 8;
                frag8 aH = *(const frag8*)&t2H[l16 * 72 + ko];
                frag8 aL = *(const frag8*)&t2L[l16 * 72 + ko];
                frag8 bH = *(const frag8*)&dhH[posbt2 * 72 + ko];
                frag8 bL = *(const frag8*)&dhL[posbt2 * 72 + ko];
                t2a = __builtin_amdgcn_mfma_f32_16x16x32_bf16(aH, bH, t2a, 0, 0, 0);
                t2a = __builtin_amdgcn_mfma_f32_16x16x32_bf16(aH, bL, t2a, 0, 0, 0);
                t2a = __builtin_amdgcn_mfma_f32_16x16x32_bf16(aL, bH, t2a, 0, 0, 0);
            }
        }
        __syncthreads();
    }

    // conv3 epilogue -> d3f[oc][px]
    if (w < 4) {
        int oc = w * 32 + ln;
        float bias = b3[oc];
#pragma unroll
        for (int r = 0; r < 16; ++r) {
            int px = (r & 3) + 8 * (r >> 2) + 4 * q;
            if (px < 16) d3f[oc * 16 + px] = fmaxf(c3[r] + bias, 0.f);
        }
    } else {
        // t2 epilogue -> scores
#pragma unroll
        for (int r = 0; r < 4; ++r) {
            int oc = q4 * 4 + r;
            if (oc < 6 && pxt2 < 49) {
                float v = t2a[r] + bt2[oc];
                sbuf[1176 + oc * 49 + pxt2] = v;
                score_out[b * NA + 1176 + oc * 49 + pxt2] = v;
            }
        }
    }
    for (int i = tid; i < 1152; i += 512) wt3s[i] = wt3[i];
    __syncthreads();

    // ================= phase C: t3 (VALU) + anchor staging =================
    if (tid < 144) {
        int oc = tid >> 4, px = tid & 15;
        float s = bt3[oc];
        for (int ic = 0; ic < 128; ++ic) s += wt3s[oc * 128 + ic] * d3f[ic * 16 + px];
        sbuf[1470 + oc * 16 + px] = s;
        score_out[b * NA + 1470 + oc * 16 + px] = s;
    }
    for (int j = tid; j < NA; j += 512) {
        int4 a = ((const int4*)anchors)[j];
        float a0 = (float)a.x, a1 = (float)a.y, a2 = (float)a.z, a3 = (float)a.w;
        y0s[j] = a0; x0s[j] = a1; y1s[j] = a2; x1s[j] = a3;
        ars[j] = (a2 - a0) * (a3 - a1);
    }
    __syncthreads();

    // ================= phase D: greedy hard-NMS top-4 (shuffle reduce) =================
    for (int it = 0; it < TOPN; ++it) {
        float bv = -INFINITY; int bi = NA;
        for (int j = tid; j < NA; j += 512) {
            float v = sbuf[j];
            if (v > bv || (v == bv && j < bi)) { bv = v; bi = j; }
        }
#pragma unroll
        for (int d = 1; d < 64; d <<= 1) {
            float ov = __shfl_xor(bv, d, 64);
            int   oi = __shfl_xor(bi, d, 64);
            if (ov > bv || (ov == bv && oi < bi)) { bv = ov; bi = oi; }
        }
        if (l == 0) { rv[w] = bv; ri[w] = bi; }
        __syncthreads();
        if (tid == 0) {
            float V = rv[0]; int K = ri[0];
#pragma unroll
            for (int j = 1; j < 8; ++j) {
                float ov = rv[j]; int oi = ri[j];
                if (ov > V || (ov == V && oi < K)) { V = ov; K = oi; }
            }
            ri[8] = K;
            out_idx[b * TOPN + it] = (float)K;
            out_prob[b * TOPN + it] = V;
            idx_ws[b * TOPN + it] = K;
        }
        __syncthreads();
        int K = ri[8];
        float ky0 = y0s[K], kx0 = x0s[K], ky1 = y1s[K], kx1 = x1s[K], ka = ars[K];
        for (int j = tid; j < NA; j += 512) {
            float iy = fmaxf(fminf(y1s[j], ky1) - fmaxf(y0s[j], ky0), 0.f);
            float ix = fmaxf(fminf(x1s[j], kx1) - fmaxf(x0s[j], kx0), 0.f);
            float inter = iy * ix;
            float iou = inter / (ars[j] + ka - inter);
            if (iou >= 0.25f) sbuf[j] = -INFINITY;
        }
        __syncthreads();
    }
}

// ---------------- bilinear crop-resize ----------------
__global__ __launch_bounds__(256) void k_crop(const float* __restrict__ x,
                                              const int* __restrict__ anchors,
                                              const int* __restrict__ idx_ws,
                                              float* __restrict__ out) {
    int blk = blockIdx.x;
    int crop = blk / OUTS;
    int i = blk % OUTS;
    int j = threadIdx.x;
    if (j >= OUTS) return;
    int b = crop >> 2;
    int a = idx_ws[crop];
    int y0 = anchors[a * 4], x0 = anchors[a * 4 + 1];
    int y1 = anchors[a * 4 + 2], x1 = anchors[a * 4 + 3];

    float ti = (float)i / 223.f;
    float ys = (float)y0 + ti * (float)(y1 - y0 - 1);
    int yi0 = (int)ys;
    int yi1 = min(yi0 + 1, HP - 1);
    float wy = ys - (float)yi0;

    float tj = (float)j / 223.f;
    float xs = (float)x0 + tj * (float)(x1 - x0 - 1);
    int xi0 = (int)xs;
    int xi1 = min(xi0 + 1, HP - 1);
    float wx = xs - (float)xi0;

    int ry0 = yi0 - PADW, ry1 = yi1 - PADW, rx0 = xi0 - PADW, rx1 = xi1 - PADW;
    bool vy0 = (ry0 >= 0) && (ry0 < IM), vy1 = (ry1 >= 0) && (ry1 < IM);
    bool vx0 = (rx0 >= 0) && (rx0 < IM), vx1 = (rx1 >= 0) && (rx1 < IM);

    float w00 = (1.f - wy) * (1.f - wx), w01 = (1.f - wy) * wx;
    float w10 = wy * (1.f - wx), w11 = wy * wx;

#pragma unroll
    for (int c = 0; c < 3; ++c) {
        const float* xp = x + (size_t)(b * 3 + c) * IM * IM;
        float g00 = (vy0 && vx0) ? xp[ry0 * IM + rx0] : 0.f;
        float g01 = (vy0 && vx1) ? xp[ry0 * IM + rx1] : 0.f;
        float g10 = (vy1 && vx0) ? xp[ry1 * IM + rx0] : 0.f;
        float g11 = (vy1 && vx1) ? xp[ry1 * IM + rx1] : 0.f;
        out[(size_t)(crop * 3 + c) * OUTS * OUTS + i * OUTS + j] =
            g00 * w00 + g01 * w01 + g10 * w10 + g11 * w11;
    }
}

extern "C" void kernel_launch(void* const* d_in, const int* in_sizes, int n_in,
                              void* d_out, int out_size, void* d_ws, size_t ws_size,
                              hipStream_t stream) {
    (void)in_sizes; (void)n_in; (void)out_size; (void)ws_size;
    const float* x    = (const float*)d_in[0];
    const float* rpn  = (const float*)d_in[1];
    const float* w1   = (const float*)d_in[2];
    const float* b1   = (const float*)d_in[3];
    const float* w2   = (const float*)d_in[4];
    const float* b2   = (const float*)d_in[5];
    const float* w3   = (const float*)d_in[6];
    const float* b3   = (const float*)d_in[7];
    const float* wt1  = (const float*)d_in[8];
    const float* bt1  = (const float*)d_in[9];
    const float* wt2  = (const float*)d_in[10];
    const float* bt2  = (const float*)d_in[11];
    const float* wt3  = (const float*)d_in[12];
    const float* bt3  = (const float*)d_in[13];
    const int*   anc  = (const int*)d_in[14];

    float* out = (float*)d_out;
    float* ws  = (float*)d_ws;
    float* d1  = ws + WS_D1;
    int*   idxw = (int*)(ws + WS_IDX);
    unsigned short* w1h = (unsigned short*)(ws + WS_WT);
    unsigned short* w1l = w1h + NWT1;
    unsigned short* w2fh = w1l + NWT1;
    unsigned short* w2fl = w2fh + NWT2;
    unsigned short* w3fh = w2fl + NWT2;
    unsigned short* w3fl = w3fh + NWT2;
    unsigned short* imgH = w3fl + NWT2;   // NIMG ushorts

    static const int TAIL_LDS = 160568;
    hipFuncSetAttribute((const void*)k_tail, hipFuncAttributeMaxDynamicSharedMemorySize, TAIL_LDS);

    k_prep<<<1160, 256, 0, stream>>>(w1, w1h, w1l, w2, w2fh, w2fl, w3, w3fh, w3fl,
                                     rpn, imgH, b1, d1);
    k_conv1_mfma<<<512, 512, 0, stream>>>(imgH, w1h, w1l, d1);
    k_tail<<<BATCH, 512, TAIL_LDS, stream>>>(d1, w2fh, w2fl, w3fh, w3fl, b2, b3,
                                             wt1, bt1, wt2, bt2, wt3, bt3, anc,
                                             out + OFF_SCORE, out + OFF_TOPIDX,
                                             out + OFF_TOPPROB, idxw);
    k_crop<<<BATCH * TOPN * OUTS, 256, 0, stream>>>(x, anc, idxw, out);
}

// Round 8
// 261.811 us; speedup vs baseline: 1.1149x; 1.0401x over previous
//
#include <hip/hip_runtime.h>
#include <math.h>

#define BATCH 16
#define TOPN 4
#define OUTS 224
#define PADW 224
#define IM 448
#define HP 896
#define NA 1614
#define IC1 2048
#define C128 128

// d_out float offsets
#define N_PART (BATCH*TOPN*3*OUTS*OUTS)       // 9,633,792
#define OFF_TOPIDX  (N_PART)
#define OFF_TOPPROB (N_PART + BATCH*TOPN)
#define OFF_SCORE   (N_PART + 2*BATCH*TOPN)

// ws float offsets.  d1 is [b][px 196][oc 128]
#define WS_D1 0
#define WS_IDX (BATCH*C128*196)                // 64 ints
#define WS_WT  (WS_IDX + 64)                   // repacked weights (ushort)
#define NWT1 (9*2048*128)
#define NWT2 (9*128*128)
#define NIMG (16*32*16384)                     // pre-swizzled conv1 input images (ushort)
#define D1SL 25088                             // 196*128 floats per partial slice

typedef __attribute__((ext_vector_type(8))) short frag8;     // 8 bf16 (4 VGPRs)
typedef __attribute__((ext_vector_type(16))) float acc16;    // 16 fp32 acc (32x32)
typedef __attribute__((ext_vector_type(4)))  float acc4;     // 4 fp32 acc (16x16)

__device__ __forceinline__ unsigned short f2bf(float f) {
    unsigned int u = __float_as_uint(f);
    u = (u + 0x7fffu + ((u >> 16) & 1u)) >> 16;   // RNE
    return (unsigned short)u;
}
__device__ __forceinline__ float bf2f(unsigned short h) {
    return __uint_as_float(((unsigned int)h) << 16);
}
__device__ __forceinline__ void cvt4(const float* v, ushort4* h, ushort4* lo) {
    unsigned short hh[4], ll[4];
#pragma unroll
    for (int e = 0; e < 4; ++e) { hh[e] = f2bf(v[e]); ll[e] = f2bf(v[e] - bf2f(hh[e])); }
    *h  = make_ushort4(hh[0], hh[1], hh[2], hh[3]);
    *lo = make_ushort4(ll[0], ll[1], ll[2], ll[3]);
}

// ---------------- fused prep ----------------
// w1 fragment-major repack, one (oc, 8-ic) pair per thread, all 9 taps.
// dst element = t*262144 + kg*16384 + h*8192 + c*2048 + ot*512 + l*8
//   with oc = ot*32 + (l&31), ic = kg*128 + h*64 + c*16 + (l>>5)*8 + e
__device__ __forceinline__ void w1frag_body(const float* __restrict__ w1,
                                            unsigned short* __restrict__ w1h,
                                            unsigned short* __restrict__ w1l,
                                            int i) {
    if (i >= 32768) return;
    int oc5 = i & 31;
    int q8  = (i >> 5) & 1;
    int ot  = (i >> 6) & 3;
    int c   = (i >> 8) & 3;
    int h   = (i >> 10) & 1;
    int kg  = (i >> 11) & 15;
    int oc  = ot * 32 + oc5;
    int ic0 = kg * 128 + h * 64 + c * 16 + q8 * 8;
    int l   = q8 * 32 + oc5;
    const float* src = w1 + ((size_t)oc * IC1 + ic0) * 9;
    size_t dbase = (size_t)kg * 16384 + h * 8192 + c * 2048 + ot * 512 + l * 8;
#pragma unroll
    for (int t = 0; t < 9; ++t) {
        frag8 hv, lv;
#pragma unroll
        for (int e = 0; e < 8; ++e) {
            float v = src[e * 9 + t];
            unsigned short hs = f2bf(v);
            hv[e] = (short)hs;
            lv[e] = (short)f2bf(v - bf2f(hs));
        }
        size_t dst = dbase + (size_t)t * 262144;
        *(frag8*)&w1h[dst] = hv;
        *(frag8*)&w1l[dst] = lv;
    }
}

// 128x128x3x3 fragment-major repack (w2, w3): dst = t*16384 + h*8192 + c*2048 + ot*512 + l*8
//   oc = ot*32 + (l&31), ic = h*64 + c*16 + (l>>5)*8 + e
__device__ __forceinline__ void wfrag128_body(const float* __restrict__ w,
                                              unsigned short* __restrict__ wh,
                                              unsigned short* __restrict__ wl,
                                              int i) {
    if (i >= 16384) return;
    int oc5 = i & 31;
    int q8  = (i >> 5) & 1;
    int ot  = (i >> 6) & 3;
    int c   = (i >> 8) & 3;
    int h   = (i >> 10) & 1;
    int oc  = ot * 32 + oc5;
    int ic0 = h * 64 + c * 16 + q8 * 8;
    int l   = q8 * 32 + oc5;
    const float* src = w + ((size_t)oc * C128 + ic0) * 9;
    size_t dbase = (size_t)h * 8192 + c * 2048 + ot * 512 + l * 8;
#pragma unroll
    for (int t = 0; t < 9; ++t) {
        frag8 hv, lv;
#pragma unroll
        for (int e = 0; e < 8; ++e) {
            float v = src[e * 9 + t];
            unsigned short hs = f2bf(v);
            hv[e] = (short)hs;
            lv[e] = (short)f2bf(v - bf2f(hs));
        }
        size_t dst = dbase + (size_t)t * 16384;
        *(frag8*)&wh[dst] = hv;
        *(frag8*)&wl[dst] = lv;
    }
}

// grid 768: [0,128) w1frag | [128,192) w2frag | [192,256) w3frag | [256,768) img
__global__ __launch_bounds__(256) void k_prep(
    const float* __restrict__ w1, unsigned short* __restrict__ w1h, unsigned short* __restrict__ w1l,
    const float* __restrict__ w2, unsigned short* __restrict__ w2fh, unsigned short* __restrict__ w2fl,
    const float* __restrict__ w3, unsigned short* __restrict__ w3fh, unsigned short* __restrict__ w3fl,
    const float* __restrict__ rpn, unsigned short* __restrict__ imgH) {
    __shared__ float tile[64 * 201];
    const int tid = threadIdx.x;
    const int blk = blockIdx.x;
    if (blk < 128) {
        w1frag_body(w1, w1h, w1l, blk * 256 + tid);
    } else if (blk < 192) {
        wfrag128_body(w2, w2fh, w2fl, (blk - 128) * 256 + tid);
    } else if (blk < 256) {
        wfrag128_body(w3, w3fh, w3fl, (blk - 192) * 256 + tid);
    } else {
        // build pre-swizzled 32KB image for slice (b, icg): [256 pos][64 ic] bf16-hi
        const int bb = blk - 256;
        const int b = bb & 15, icg = bb >> 4;
        const int ic0 = icg * 64;
        char* img = (char*)(imgH + (size_t)bb * 16384);   // slice index = icg*16 + b
        for (int qq = tid; qq < 3136; qq += 256) {
            int icl = qq / 49, r = qq % 49, p = r * 4;
            const float4 v = *(const float4*)&rpn[(size_t)(b * IC1 + ic0 + icl) * 196 + p];
            tile[icl * 201 + p + 0] = v.x;
            tile[icl * 201 + p + 1] = v.y;
            tile[icl * 201 + p + 2] = v.z;
            tile[icl * 201 + p + 3] = v.w;
        }
        __syncthreads();
        // data cells: pos = (px/14+1)*16 + (px%14+1), XOR-swizzled byte layout
        for (int qq = tid; qq < 3136; qq += 256) {
            int px = qq >> 4, ic4 = (qq & 15) * 4;
            float vv[4];
            unsigned short hh[4];
#pragma unroll
            for (int e = 0; e < 4; ++e) { vv[e] = tile[(ic4 + e) * 201 + px]; hh[e] = f2bf(vv[e]); }
            int pos = (px / 14 + 1) * 16 + (px % 14 + 1);
            int byo = (pos * 128 + ic4 * 2) ^ ((pos & 7) << 4);
            *(ushort4*)(img + byo) = make_ushort4(hh[0], hh[1], hh[2], hh[3]);
        }
        // halo cells: 60 positions, zero full 128B rows (swizzle-invariant)
        for (int qq = tid; qq < 960; qq += 256) {
            int hp = qq >> 4, sub = qq & 15;
            int pos;
            if (hp < 16)      pos = hp;                       // row 0
            else if (hp < 32) pos = 240 + (hp - 16);          // row 15
            else if (hp < 46) pos = (hp - 31) * 16;           // col 0, rows 1..14
            else              pos = (hp - 45) * 16 + 15;      // col 15, rows 1..14
            *(ushort4*)(img + pos * 128 + sub * 8) = make_ushort4(0, 0, 0, 0);
        }
    }
}

// ---------------- conv1 via MFMA 32x32x16 bf16, 2-term (input bf16, weight hi+lo) -------
// Grid 512: blk = b*32 + icg  (XCD = icg%8 -> per-XCD weight set 4 slices = 1.2MB, L2-hot)
// Wave tile 128px x 32oc; per iter: 4 A-ds + 2 B-vmem + 8 MFMA; 3-deep B ring.
// Epilogue: PLAIN coalesced stores of partials to d1p[blk] (atomics removed; A/B vs r7).

#define LOADB(it, BH, BL) { \
    const int o_ = ((it) >> 2) * 262144 + ((it) & 3) * 2048; \
    BH = *(const frag8*)&WHb[o_]; BL = *(const frag8*)&WLb[o_]; }

#define DOMFMA(it, BH, BL) { \
    const int tap_ = (it) >> 2; \
    const int off_ = (tap_ / 3) * 16 + (tap_ % 3); \
    const int kb_ = ((it) & 3) * 32 + q * 16; \
    frag8 aH[4]; \
    _Pragma("unroll") \
    for (int mt_ = 0; mt_ < 4; ++mt_) { \
        const int p_ = posa[mt_] + off_; \
        const int by_ = (p_ * 128 + kb_) ^ ((p_ & 7) << 4); \
        aH[mt_] = *(const frag8*)((const char*)inH + by_); \
    } \
    _Pragma("unroll") \
    for (int mt_ = 0; mt_ < 4; ++mt_) { \
        acc[mt_] = __builtin_amdgcn_mfma_f32_32x32x16_bf16(aH[mt_], BH, acc[mt_], 0, 0, 0); \
        acc[mt_] = __builtin_amdgcn_mfma_f32_32x32x16_bf16(aH[mt_], BL, acc[mt_], 0, 0, 0); \
    } }

__global__ __launch_bounds__(512, 4) void k_conv1_mfma(const unsigned short* __restrict__ imgH,
                                                       const unsigned short* __restrict__ wfh,
                                                       const unsigned short* __restrict__ wfl,
                                                       float* __restrict__ d1p) {
    __shared__ unsigned short inH[256 * 64];   // 32KB pre-swizzled [pos][ic64] bf16-hi

    const int tid = threadIdx.x;
    const int blk = blockIdx.x;
    const int b = blk >> 5;
    const int icg = blk & 31;
    const int l = tid & 63, w = tid >> 6;
    const int ln = l & 31, q = l >> 5;
    const int mtw = w & 1, ntw = w >> 1;   // 2 px-halves x 4 oc-tiles

    // stage: linear coalesced copy of the image (halo + swizzle pre-baked); slice = icg*16+b
    {
        const char* src = (const char*)(imgH + ((size_t)(icg * 16 + b)) * 16384);
        char* dst = (char*)inH;
#pragma unroll
        for (int k = 0; k < 4; ++k) {
            frag8 v = *(const frag8*)(src + tid * 16 + k * 8192);
            *(frag8*)(dst + tid * 16 + k * 8192) = v;
        }
    }

    acc16 acc[4];
#pragma unroll
    for (int mt = 0; mt < 4; ++mt)
#pragma unroll
        for (int r = 0; r < 16; ++r) acc[mt][r] = 0.f;

    int posa[4];
#pragma unroll
    for (int mt = 0; mt < 4; ++mt) {
        int px = mtw * 128 + mt * 32 + ln;
        posa[mt] = (px < 196) ? ((px / 14) * 16 + (px % 14)) : 0;  // invalid -> halo zeros
    }

    // fragment-major weight base: + tap*262144 + c*2048
    const unsigned short* WHb = wfh + (size_t)icg * 8192 + ntw * 512 + (size_t)l * 8;
    const unsigned short* WLb = wfl + (size_t)icg * 8192 + ntw * 512 + (size_t)l * 8;

    __syncthreads();

    // 36 iterations (9 taps x 4 c), 3-deep B ring, barrier-free
    frag8 B0H, B0L, B1H, B1L, B2H, B2L;
    LOADB(0, B0H, B0L);
    LOADB(1, B1H, B1L);
    LOADB(2, B2H, B2L);
#pragma unroll
    for (int g = 0; g < 12; ++g) {
        DOMFMA(g * 3 + 0, B0H, B0L); if (g < 11) LOADB(g * 3 + 3, B0H, B0L);
        DOMFMA(g * 3 + 1, B1H, B1L); if (g < 11) LOADB(g * 3 + 4, B1H, B1L);
        DOMFMA(g * 3 + 2, B2H, B2L); if (g < 11) LOADB(g * 3 + 5, B2H, B2L);
    }

    // epilogue: plain partial-sum stores (coalesced along oc), no atomics
    {
        float* out = d1p + (size_t)blk * D1SL;
        const int oc = ntw * 32 + ln;
#pragma unroll
        for (int mt = 0; mt < 4; ++mt) {
#pragma unroll
            for (int r = 0; r < 16; ++r) {
                int m = (r & 3) + 8 * (r >> 2) + 4 * q;
                int px = mtw * 128 + mt * 32 + m;
                if (px < 196)
                    out[px * 128 + oc] = acc[mt][r];
            }
        }
    }
}

// ---------------- reduce: d1 = relu(b1 + sum over 32 icg slices) ----------------
// grid 392 x 256 threads, one float4 per thread (16*25088/4 = 100352 float4s)
__global__ __launch_bounds__(256) void k_reduce(const float* __restrict__ d1p,
                                                const float* __restrict__ b1,
                                                float* __restrict__ d1) {
    int f4 = blockIdx.x * 256 + threadIdx.x;
    int flat = f4 * 4;
    int b = flat / D1SL;
    int inner = flat - b * D1SL;
    const float* src = d1p + (size_t)b * 32 * D1SL + inner;
    float4 s = *(const float4*)&b1[inner & 127];
#pragma unroll 8
    for (int icg = 0; icg < 32; ++icg) {
        float4 v = *(const float4*)&src[(size_t)icg * D1SL];
        s.x += v.x; s.y += v.y; s.z += v.z; s.w += v.w;
    }
    s.x = fmaxf(s.x, 0.f); s.y = fmaxf(s.y, 0.f);
    s.z = fmaxf(s.z, 0.f); s.w = fmaxf(s.w, 0.f);
    *(float4*)&d1[flat] = s;
}

// ---------------- fused tail: conv2+conv3+tidy+NMS, one 512-thread block per batch -------
// conv2/conv3 B-operands reg-direct from L2 (frag-major), 4-deep ring, barrier-free inner loops.

#define LOADB2(it, BH, BL) { \
    const int o_ = ((it) >> 2) * 16384 + ((it) & 3) * 2048; \
    BH = *(const frag8*)&W2H[o_]; BL = *(const frag8*)&W2L[o_]; }

#define DOC2(it, BH, BL) { \
    const int tap_ = (it) >> 2; \
    const int off_ = (tap_ / 3) * 16 + (tap_ % 3); \
    const int ko_ = ((it) & 3) * 16 + q * 8; \
    const int pp_ = (posa2 + off_) * 72 + ko_; \
    frag8 aH = *(const frag8*)&inH[pp_]; \
    frag8 aL = *(const frag8*)&inL[pp_]; \
    c2 = __builtin_amdgcn_mfma_f32_32x32x16_bf16(aH, BH, c2, 0, 0, 0); \
    c2 = __builtin_amdgcn_mfma_f32_32x32x16_bf16(aH, BL, c2, 0, 0, 0); \
    c2 = __builtin_amdgcn_mfma_f32_32x32x16_bf16(aL, BH, c2, 0, 0, 0); }

#define LOADB3(it, BH, BL) { \
    const int o_ = ((it) >> 2) * 16384 + ((it) & 3) * 2048; \
    BH = *(const frag8*)&W3Hp[o_]; BL = *(const frag8*)&W3Lp[o_]; }

#define DOC3(it, BH, BL) { \
    const int tap_ = (it) >> 2; \
    const int off_ = (tap_ / 3) * 16 + (tap_ % 3); \
    const int ko_ = ((it) & 3) * 16 + q * 8; \
    const int pp_ = (posb3 + off_) * 72 + ko_; \
    frag8 aH = *(const frag8*)&dhH[pp_]; \
    frag8 aL = *(const frag8*)&dhL[pp_]; \
    c3 = __builtin_amdgcn_mfma_f32_32x32x16_bf16(aH, BH, c3, 0, 0, 0); \
    c3 = __builtin_amdgcn_mfma_f32_32x32x16_bf16(aH, BL, c3, 0, 0, 0); \
    c3 = __builtin_amdgcn_mfma_f32_32x32x16_bf16(aL, BH, c3, 0, 0, 0); }

__global__ __launch_bounds__(512, 1) void k_tail(
    const float* __restrict__ d1,
    const unsigned short* __restrict__ w2fh, const unsigned short* __restrict__ w2fl,
    const unsigned short* __restrict__ w3fh, const unsigned short* __restrict__ w3fl,
    const float* __restrict__ b2, const float* __restrict__ b3,
    const float* __restrict__ wt1, const float* __restrict__ bt1,
    const float* __restrict__ wt2, const float* __restrict__ bt2,
    const float* __restrict__ wt3, const float* __restrict__ bt3,
    const int* __restrict__ anchors,
    float* __restrict__ score_out, float* __restrict__ out_idx,
    float* __restrict__ out_prob, int* __restrict__ idx_ws) {
    extern __shared__ char smem[];
    unsigned short* inH = (unsigned short*)(smem);            // [pos 304][ic 72]
    unsigned short* inL = (unsigned short*)(smem + 43776);
    unsigned short* t1H = (unsigned short*)(smem + 124416);   // [oc16][ic 72]
    unsigned short* t1L = (unsigned short*)(smem + 126720);
    float*  d2f  = (float*)(smem + 129024);                   // [px 49][oc 128]
    float*  sbuf = (float*)(smem + 154112);                   // [1614]
    unsigned short* dhH = (unsigned short*)(smem);            // [pos 192][ic 72]
    unsigned short* dhL = (unsigned short*)(smem + 27648);
    float*  d3f  = (float*)(smem + 55296);                    // [oc 128][px 16]
    unsigned short* t2H = (unsigned short*)(smem + 63488);
    unsigned short* t2L = (unsigned short*)(smem + 65792);
    float* wt3s = (float*)(smem);
    float* y0s = (float*)(smem + 6464);
    float* x0s = (float*)(smem + 12928);
    float* y1s = (float*)(smem + 19392);
    float* x1s = (float*)(smem + 25856);
    float* ars = (float*)(smem + 32320);
    float* rv  = (float*)(smem + 38784);
    int*   ri  = (int*)(smem + 39808);

    const int tid = threadIdx.x;           // 0..511, 8 waves
    const int b = blockIdx.x;
    const int l = tid & 63, w = tid >> 6;
    const int ln = l & 31, q = l >> 5;
    const int l16 = l & 15, q4 = l >> 4;

    // ================= phase A: conv2 + t1 =================
    for (int i = tid; i < 304 * 72; i += 512) { inH[i] = 0; inL[i] = 0; }

    acc16 c2;
    acc4 t1a[2];
#pragma unroll
    for (int r = 0; r < 16; ++r) c2[r] = 0.f;
#pragma unroll
    for (int i = 0; i < 2; ++i)
#pragma unroll
        for (int r = 0; r < 4; ++r) t1a[i][r] = 0.f;

    const int mtw = w & 1, ntw = w >> 1;   // 2 px-tiles x 4 oc-tiles
    int posa2;
    {
        int px = mtw * 32 + ln;
        posa2 = (px < 49) ? ((px / 7) * 32 + (px % 7) * 2) : 256;
    }
    __syncthreads();

    for (int half = 0; half < 2; ++half) {
        const int ics = half * 64;
        for (int qq = tid; qq < 3136; qq += 512) {
            int px = qq >> 4, ic4 = (qq & 15) * 4;
            float4 v = *(const float4*)&d1[(size_t)(b * 196 + px) * 128 + ics + ic4];
            float vv[4] = {fmaxf(v.x, 0.f), fmaxf(v.y, 0.f), fmaxf(v.z, 0.f), fmaxf(v.w, 0.f)};
            ushort4 h4, l4; cvt4(vv, &h4, &l4);
            int pos = (px / 14 + 1) * 16 + (px % 14 + 1);
            *(ushort4*)&inH[pos * 72 + ic4] = h4;
            *(ushort4*)&inL[pos * 72 + ic4] = l4;
        }
        for (int qq = tid; qq < 1024; qq += 512) {
            int m = qq >> 6, k = qq & 63;
            float v = (m < 6) ? wt1[m * 128 + ics + k] : 0.f;
            unsigned short h = f2bf(v);
            t1H[m * 72 + k] = h;
            t1L[m * 72 + k] = f2bf(v - bf2f(h));
        }
        __syncthreads();

        // barrier-free conv2: 36 iters (9 taps x 4 c), 4-deep B ring from L2
        {
            const unsigned short* W2H = w2fh + half * 8192 + ntw * 512 + (size_t)l * 8;
            const unsigned short* W2L = w2fl + half * 8192 + ntw * 512 + (size_t)l * 8;
            frag8 B0H, B0L, B1H, B1L, B2H, B2L, B3H, B3L;
            LOADB2(0, B0H, B0L);
            LOADB2(1, B1H, B1L);
            LOADB2(2, B2H, B2L);
            LOADB2(3, B3H, B3L);
#pragma unroll
            for (int g = 0; g < 9; ++g) {
                DOC2(g * 4 + 0, B0H, B0L); if (g < 8) LOADB2(g * 4 + 4, B0H, B0L);
                DOC2(g * 4 + 1, B1H, B1L); if (g < 8) LOADB2(g * 4 + 5, B1H, B1L);
                DOC2(g * 4 + 2, B2H, B2L); if (g < 8) LOADB2(g * 4 + 6, B2H, B2L);
                DOC2(g * 4 + 3, B3H, B3L); if (g < 8) LOADB2(g * 4 + 7, B3H, B3L);
            }
        }

        // t1 MFMA on this half (inH intact; no one wrote LDS since stage barrier)
#pragma unroll
        for (int i = 0; i < 2; ++i) {
            int px = (w * 2 + i) * 16 + l16;
            int pos = (px < 196) ? ((px / 14 + 1) * 16 + (px % 14 + 1)) : 256;
#pragma unroll
            for (int c = 0; c < 2; ++c) {
                int ko = c * 32 + q4 * 8;
                frag8 aH = *(const frag8*)&t1H[l16 * 72 + ko];
                frag8 aL = *(const frag8*)&t1L[l16 * 72 + ko];
                frag8 bH = *(const frag8*)&inH[pos * 72 + ko];
                frag8 bL = *(const frag8*)&inL[pos * 72 + ko];
                t1a[i] = __builtin_amdgcn_mfma_f32_16x16x32_bf16(aH, bH, t1a[i], 0, 0, 0);
                t1a[i] = __builtin_amdgcn_mfma_f32_16x16x32_bf16(aH, bL, t1a[i], 0, 0, 0);
                t1a[i] = __builtin_amdgcn_mfma_f32_16x16x32_bf16(aL, bH, t1a[i], 0, 0, 0);
            }
        }
        __syncthreads();
    }

    // conv2 epilogue -> d2f[px][oc]
    {
        int oc = ntw * 32 + ln;
        float bias = b2[oc];
#pragma unroll
        for (int r = 0; r < 16; ++r) {
            int m = (r & 3) + 8 * (r >> 2) + 4 * q;
            int px = mtw * 32 + m;
            if (px < 49) d2f[px * 128 + oc] = fmaxf(c2[r] + bias, 0.f);
        }
    }
    // t1 epilogue -> scores
#pragma unroll
    for (int i = 0; i < 2; ++i) {
        int px = (w * 2 + i) * 16 + l16;
#pragma unroll
        for (int r = 0; r < 4; ++r) {
            int oc = q4 * 4 + r;
            if (oc < 6 && px < 196) {
                float v = t1a[i][r] + bt1[oc];
                sbuf[oc * 196 + px] = v;
                score_out[b * NA + oc * 196 + px] = v;
            }
        }
    }
    __syncthreads();

    // ================= phase B: conv3 (waves 0-3) + t2 (waves 4-7) =================
    for (int i = tid; i < 192 * 72; i += 512) { dhH[i] = 0; dhL[i] = 0; }

    acc16 c3;
    acc4 t2a;
#pragma unroll
    for (int r = 0; r < 16; ++r) c3[r] = 0.f;
#pragma unroll
    for (int r = 0; r < 4; ++r) t2a[r] = 0.f;

    const int posb3 = (ln < 16) ? ((ln / 4) * 32 + (ln % 4) * 2) : 144;
    const int pxt2 = (w - 4) * 16 + l16;   // valid for w>=4
    const int posbt2 = (w >= 4 && pxt2 < 49) ? ((pxt2 / 7 + 1) * 16 + (pxt2 % 7 + 1)) : 144;
    __syncthreads();

    for (int half = 0; half < 2; ++half) {
        const int ics = half * 64;
        for (int qq = tid; qq < 784; qq += 512) {
            int px = qq >> 4, ic4 = (qq & 15) * 4;
            float4 v = *(const float4*)&d2f[px * 128 + ics + ic4];
            float vv[4] = {v.x, v.y, v.z, v.w};
            ushort4 h4, l4; cvt4(vv, &h4, &l4);
            int pos = (px / 7 + 1) * 16 + (px % 7 + 1);
            *(ushort4*)&dhH[pos * 72 + ic4] = h4;
            *(ushort4*)&dhL[pos * 72 + ic4] = l4;
        }
        for (int qq = tid; qq < 1024; qq += 512) {
            int m = qq >> 6, k = qq & 63;
            float v = (m < 6) ? wt2[m * 128 + ics + k] : 0.f;
            unsigned short h = f2bf(v);
            t2H[m * 72 + k] = h;
            t2L[m * 72 + k] = f2bf(v - bf2f(h));
        }
        __syncthreads();

        if (w < 4) {
            // barrier-free conv3: 36 iters, 4-deep B ring; ot = w
            const unsigned short* W3Hp = w3fh + half * 8192 + w * 512 + (size_t)l * 8;
            const unsigned short* W3Lp = w3fl + half * 8192 + w * 512 + (size_t)l * 8;
            frag8 B0H, B0L, B1H, B1L, B2H, B2L, B3H, B3L;
            LOADB3(0, B0H, B0L);
            LOADB3(1, B1H, B1L);
            LOADB3(2, B2H, B2L);
            LOADB3(3, B3H, B3L);
#pragma unroll
            for (int g = 0; g < 9; ++g) {
                DOC3(g * 4 + 0, B0H, B0L); if (g < 8) LOADB3(g * 4 + 4, B0H, B0L);
                DOC3(g * 4 + 1, B1H, B1L); if (g < 8) LOADB3(g * 4 + 5, B1H, B1L);
                DOC3(g * 4 + 2, B2H, B2L); if (g < 8) LOADB3(g * 4 + 6, B2H, B2L);
                DOC3(g * 4 + 3, B3H, B3L); if (g < 8) LOADB3(g * 4 + 7, B3H, B3L);
            }
        } else {
            // t2 on this half (dh stable until end-of-half barrier)
#pragma unroll
            for (int c = 0; c < 2; ++c) {
                int ko = c * 32 + q4 * 8;
                frag8 aH = *(const frag8*)&t2H[l16 * 72 + ko];
                frag8 aL = *(const frag8*)&t2L[l16 * 72 + ko];
                frag8 bH = *(const frag8*)&dhH[posbt2 * 72 + ko];
                frag8 bL = *(const frag8*)&dhL[posbt2 * 72 + ko];
                t2a = __builtin_amdgcn_mfma_f32_16x16x32_bf16(aH, bH, t2a, 0, 0, 0);
                t2a = __builtin_amdgcn_mfma_f32_16x16x32_bf16(aH, bL, t2a, 0, 0, 0);
                t2a = __builtin_amdgcn_mfma_f32_16x16x32_bf16(aL, bH, t2a, 0, 0, 0);
            }
        }
        __syncthreads();
    }

    // conv3 epilogue -> d3f[oc][px]
    if (w < 4) {
        int oc = w * 32 + ln;
        float bias = b3[oc];
#pragma unroll
        for (int r = 0; r < 16; ++r) {
            int px = (r & 3) + 8 * (r >> 2) + 4 * q;
            if (px < 16) d3f[oc * 16 + px] = fmaxf(c3[r] + bias, 0.f);
        }
    } else {
        // t2 epilogue -> scores
#pragma unroll
        for (int r = 0; r < 4; ++r) {
            int oc = q4 * 4 + r;
            if (oc < 6 && pxt2 < 49) {
                float v = t2a[r] + bt2[oc];
                sbuf[1176 + oc * 49 + pxt2] = v;
                score_out[b * NA + 1176 + oc * 49 + pxt2] = v;
            }
        }
    }
    for (int i = tid; i < 1152; i += 512) wt3s[i] = wt3[i];
    __syncthreads();

    // ================= phase C: t3 (VALU) + anchor staging =================
    if (tid < 144) {
        int oc = tid >> 4, px = tid & 15;
        float s = bt3[oc];
        for (int ic = 0; ic < 128; ++ic) s += wt3s[oc * 128 + ic] * d3f[ic * 16 + px];
        sbuf[1470 + oc * 16 + px] = s;
        score_out[b * NA + 1470 + oc * 16 + px] = s;
    }
    for (int j = tid; j < NA; j += 512) {
        int4 a = ((const int4*)anchors)[j];
        float a0 = (float)a.x, a1 = (float)a.y, a2 = (float)a.z, a3 = (float)a.w;
        y0s[j] = a0; x0s[j] = a1; y1s[j] = a2; x1s[j] = a3;
        ars[j] = (a2 - a0) * (a3 - a1);
    }
    __syncthreads();

    // ================= phase D: greedy hard-NMS top-4 (shuffle reduce) =================
    for (int it = 0; it < TOPN; ++it) {
        float bv = -INFINITY; int bi = NA;
        for (int j = tid; j < NA; j += 512) {
            float v = sbuf[j];
            if (v > bv || (v == bv && j < bi)) { bv = v; bi = j; }
        }
#pragma unroll
        for (int d = 1; d < 64; d <<= 1) {
            float ov = __shfl_xor(bv, d, 64);
            int   oi = __shfl_xor(bi, d, 64);
            if (ov > bv || (ov == bv && oi < bi)) { bv = ov; bi = oi; }
        }
        if (l == 0) { rv[w] = bv; ri[w] = bi; }
        __syncthreads();
        if (tid == 0) {
            float V = rv[0]; int K = ri[0];
#pragma unroll
            for (int j = 1; j < 8; ++j) {
                float ov = rv[j]; int oi = ri[j];
                if (ov > V || (ov == V && oi < K)) { V = ov; K = oi; }
            }
            ri[8] = K;
            out_idx[b * TOPN + it] = (float)K;
            out_prob[b * TOPN + it] = V;
            idx_ws[b * TOPN + it] = K;
        }
        __syncthreads();
        int K = ri[8];
        float ky0 = y0s[K], kx0 = x0s[K], ky1 = y1s[K], kx1 = x1s[K], ka = ars[K];
        for (int j = tid; j < NA; j += 512) {
            float iy = fmaxf(fminf(y1s[j], ky1) - fmaxf(y0s[j], ky0), 0.f);
            float ix = fmaxf(fminf(x1s[j], kx1) - fmaxf(x0s[j], kx0), 0.f);
            float inter = iy * ix;
            float iou = inter / (ars[j] + ka - inter);
            if (iou >= 0.25f) sbuf[j] = -INFINITY;
        }
        __syncthreads();
    }
}

// ---------------- bilinear crop-resize ----------------
__global__ __launch_bounds__(256) void k_crop(const float* __restrict__ x,
                                              const int* __restrict__ anchors,
                                              const int* __restrict__ idx_ws,
                                              float* __restrict__ out) {
    int blk = blockIdx.x;
    int crop = blk / OUTS;
    int i = blk % OUTS;
    int j = threadIdx.x;
    if (j >= OUTS) return;
    int b = crop >> 2;
    int a = idx_ws[crop];
    int y0 = anchors[a * 4], x0 = anchors[a * 4 + 1];
    int y1 = anchors[a * 4 + 2], x1 = anchors[a * 4 + 3];

    float ti = (float)i / 223.f;
    float ys = (float)y0 + ti * (float)(y1 - y0 - 1);
    int yi0 = (int)ys;
    int yi1 = min(yi0 + 1, HP - 1);
    float wy = ys - (float)yi0;

    float tj = (float)j / 223.f;
    float xs = (float)x0 + tj * (float)(x1 - x0 - 1);
    int xi0 = (int)xs;
    int xi1 = min(xi0 + 1, HP - 1);
    float wx = xs - (float)xi0;

    int ry0 = yi0 - PADW, ry1 = yi1 - PADW, rx0 = xi0 - PADW, rx1 = xi1 - PADW;
    bool vy0 = (ry0 >= 0) && (ry0 < IM), vy1 = (ry1 >= 0) && (ry1 < IM);
    bool vx0 = (rx0 >= 0) && (rx0 < IM), vx1 = (rx1 >= 0) && (rx1 < IM);

    float w00 = (1.f - wy) * (1.f - wx), w01 = (1.f - wy) * wx;
    float w10 = wy * (1.f - wx), w11 = wy * wx;

#pragma unroll
    for (int c = 0; c < 3; ++c) {
        const float* xp = x + (size_t)(b * 3 + c) * IM * IM;
        float g00 = (vy0 && vx0) ? xp[ry0 * IM + rx0] : 0.f;
        float g01 = (vy0 && vx1) ? xp[ry0 * IM + rx1] : 0.f;
        float g10 = (vy1 && vx0) ? xp[ry1 * IM + rx0] : 0.f;
        float g11 = (vy1 && vx1) ? xp[ry1 * IM + rx1] : 0.f;
        out[(size_t)(crop * 3 + c) * OUTS * OUTS + i * OUTS + j] =
            g00 * w00 + g01 * w01 + g10 * w10 + g11 * w11;
    }
}

extern "C" void kernel_launch(void* const* d_in, const int* in_sizes, int n_in,
                              void* d_out, int out_size, void* d_ws, size_t ws_size,
                              hipStream_t stream) {
    (void)in_sizes; (void)n_in; (void)out_size; (void)ws_size;
    const float* x    = (const float*)d_in[0];
    const float* rpn  = (const float*)d_in[1];
    const float* w1   = (const float*)d_in[2];
    const float* b1   = (const float*)d_in[3];
    const float* w2   = (const float*)d_in[4];
    const float* b2   = (const float*)d_in[5];
    const float* w3   = (const float*)d_in[6];
    const float* b3   = (const float*)d_in[7];
    const float* wt1  = (const float*)d_in[8];
    const float* bt1  = (const float*)d_in[9];
    const float* wt2  = (const float*)d_in[10];
    const float* bt2  = (const float*)d_in[11];
    const float* wt3  = (const float*)d_in[12];
    const float* bt3  = (const float*)d_in[13];
    const int*   anc  = (const int*)d_in[14];

    float* out = (float*)d_out;
    float* ws  = (float*)d_ws;
    float* d1  = ws + WS_D1;
    int*   idxw = (int*)(ws + WS_IDX);
    unsigned short* w1h = (unsigned short*)(ws + WS_WT);
    unsigned short* w1l = w1h + NWT1;
    unsigned short* w2fh = w1l + NWT1;
    unsigned short* w2fl = w2fh + NWT2;
    unsigned short* w3fh = w2fl + NWT2;
    unsigned short* w3fl = w3fh + NWT2;
    unsigned short* imgH = w3fl + NWT2;   // NIMG ushorts
    float* d1p = (float*)(imgH + NIMG);   // 512 * 25088 floats (51.4 MB partials)

    static const int TAIL_LDS = 160568;
    hipFuncSetAttribute((const void*)k_tail, hipFuncAttributeMaxDynamicSharedMemorySize, TAIL_LDS);

    k_prep<<<768, 256, 0, stream>>>(w1, w1h, w1l, w2, w2fh, w2fl, w3, w3fh, w3fl,
                                    rpn, imgH);
    k_conv1_mfma<<<512, 512, 0, stream>>>(imgH, w1h, w1l, d1p);
    k_reduce<<<392, 256, 0, stream>>>(d1p, b1, d1);
    k_tail<<<BATCH, 512, TAIL_LDS, stream>>>(d1, w2fh, w2fl, w3fh, w3fl, b2, b3,
                                             wt1, bt1, wt2, bt2, wt3, bt3, anc,
                                             out + OFF_SCORE, out + OFF_TOPIDX,
                                             out + OFF_TOPPROB, idxw);
    k_crop<<<BATCH * TOPN * OUTS, 256, 0, stream>>>(x, anc, idxw, out);
}

// Round 9
// 257.636 us; speedup vs baseline: 1.1329x; 1.0162x over previous
//
#include <hip/hip_runtime.h>
#include <math.h>

#define BATCH 16
#define TOPN 4
#define OUTS 224
#define PADW 224
#define IM 448
#define HP 896
#define NA 1614
#define IC1 2048
#define C128 128

// d_out float offsets
#define N_PART (BATCH*TOPN*3*OUTS*OUTS)       // 9,633,792
#define OFF_TOPIDX  (N_PART)
#define OFF_TOPPROB (N_PART + BATCH*TOPN)
#define OFF_SCORE   (N_PART + 2*BATCH*TOPN)

// ws float offsets.  d1 is [b][px 196][oc 128]
#define WS_D1 0
#define WS_IDX (BATCH*C128*196)                // 64 ints
#define WS_WT  (WS_IDX + 64)                   // repacked weights (ushort)
#define NWT1 (9*2048*128)
#define NWT2 (9*128*128)
#define NIMG (16*32*16384)                     // pre-swizzled conv1 input images (ushort)
#define D1SL 25088                             // 196*128 floats per partial slice

typedef __attribute__((ext_vector_type(8))) short frag8;     // 8 bf16 (4 VGPRs)
typedef __attribute__((ext_vector_type(16))) float acc16;    // 16 fp32 acc (32x32)
typedef __attribute__((ext_vector_type(4)))  float acc4;     // 4 fp32 acc (16x16)

__device__ __forceinline__ unsigned short f2bf(float f) {
    unsigned int u = __float_as_uint(f);
    u = (u + 0x7fffu + ((u >> 16) & 1u)) >> 16;   // RNE
    return (unsigned short)u;
}
__device__ __forceinline__ float bf2f(unsigned short h) {
    return __uint_as_float(((unsigned int)h) << 16);
}
__device__ __forceinline__ void cvt4(const float* v, ushort4* h, ushort4* lo) {
    unsigned short hh[4], ll[4];
#pragma unroll
    for (int e = 0; e < 4; ++e) { hh[e] = f2bf(v[e]); ll[e] = f2bf(v[e] - bf2f(hh[e])); }
    *h  = make_ushort4(hh[0], hh[1], hh[2], hh[3]);
    *lo = make_ushort4(ll[0], ll[1], ll[2], ll[3]);
}

// ---------------- fused prep ----------------
// w1 fragment-major repack, one (oc, 8-ic) pair per thread, all 9 taps.
__device__ __forceinline__ void w1frag_body(const float* __restrict__ w1,
                                            unsigned short* __restrict__ w1h,
                                            unsigned short* __restrict__ w1l,
                                            int i) {
    if (i >= 32768) return;
    int oc5 = i & 31;
    int q8  = (i >> 5) & 1;
    int ot  = (i >> 6) & 3;
    int c   = (i >> 8) & 3;
    int h   = (i >> 10) & 1;
    int kg  = (i >> 11) & 15;
    int oc  = ot * 32 + oc5;
    int ic0 = kg * 128 + h * 64 + c * 16 + q8 * 8;
    int l   = q8 * 32 + oc5;
    const float* src = w1 + ((size_t)oc * IC1 + ic0) * 9;
    size_t dbase = (size_t)kg * 16384 + h * 8192 + c * 2048 + ot * 512 + l * 8;
#pragma unroll
    for (int t = 0; t < 9; ++t) {
        frag8 hv, lv;
#pragma unroll
        for (int e = 0; e < 8; ++e) {
            float v = src[e * 9 + t];
            unsigned short hs = f2bf(v);
            hv[e] = (short)hs;
            lv[e] = (short)f2bf(v - bf2f(hs));
        }
        size_t dst = dbase + (size_t)t * 262144;
        *(frag8*)&w1h[dst] = hv;
        *(frag8*)&w1l[dst] = lv;
    }
}

// 128x128x3x3 fragment-major repack (w2, w3): dst = t*16384 + h*8192 + c*2048 + ot*512 + l*8
__device__ __forceinline__ void wfrag128_body(const float* __restrict__ w,
                                              unsigned short* __restrict__ wh,
                                              unsigned short* __restrict__ wl,
                                              int i) {
    if (i >= 16384) return;
    int oc5 = i & 31;
    int q8  = (i >> 5) & 1;
    int ot  = (i >> 6) & 3;
    int c   = (i >> 8) & 3;
    int h   = (i >> 10) & 1;
    int oc  = ot * 32 + oc5;
    int ic0 = h * 64 + c * 16 + q8 * 8;
    int l   = q8 * 32 + oc5;
    const float* src = w + ((size_t)oc * C128 + ic0) * 9;
    size_t dbase = (size_t)h * 8192 + c * 2048 + ot * 512 + l * 8;
#pragma unroll
    for (int t = 0; t < 9; ++t) {
        frag8 hv, lv;
#pragma unroll
        for (int e = 0; e < 8; ++e) {
            float v = src[e * 9 + t];
            unsigned short hs = f2bf(v);
            hv[e] = (short)hs;
            lv[e] = (short)f2bf(v - bf2f(hs));
        }
        size_t dst = dbase + (size_t)t * 16384;
        *(frag8*)&wh[dst] = hv;
        *(frag8*)&wl[dst] = lv;
    }
}

// grid 768: [0,128) w1frag | [128,192) w2frag | [192,256) w3frag | [256,768) img
__global__ __launch_bounds__(256) void k_prep(
    const float* __restrict__ w1, unsigned short* __restrict__ w1h, unsigned short* __restrict__ w1l,
    const float* __restrict__ w2, unsigned short* __restrict__ w2fh, unsigned short* __restrict__ w2fl,
    const float* __restrict__ w3, unsigned short* __restrict__ w3fh, unsigned short* __restrict__ w3fl,
    const float* __restrict__ rpn, unsigned short* __restrict__ imgH) {
    __shared__ float tile[64 * 201];
    const int tid = threadIdx.x;
    const int blk = blockIdx.x;
    if (blk < 128) {
        w1frag_body(w1, w1h, w1l, blk * 256 + tid);
    } else if (blk < 192) {
        wfrag128_body(w2, w2fh, w2fl, (blk - 128) * 256 + tid);
    } else if (blk < 256) {
        wfrag128_body(w3, w3fh, w3fl, (blk - 192) * 256 + tid);
    } else {
        // build pre-swizzled 32KB image for slice (b, icg): [256 pos][64 ic] bf16-hi
        const int bb = blk - 256;
        const int b = bb & 15, icg = bb >> 4;
        const int ic0 = icg * 64;
        char* img = (char*)(imgH + (size_t)bb * 16384);   // slice index = icg*16 + b
        for (int qq = tid; qq < 3136; qq += 256) {
            int icl = qq / 49, r = qq % 49, p = r * 4;
            const float4 v = *(const float4*)&rpn[(size_t)(b * IC1 + ic0 + icl) * 196 + p];
            tile[icl * 201 + p + 0] = v.x;
            tile[icl * 201 + p + 1] = v.y;
            tile[icl * 201 + p + 2] = v.z;
            tile[icl * 201 + p + 3] = v.w;
        }
        __syncthreads();
        for (int qq = tid; qq < 3136; qq += 256) {
            int px = qq >> 4, ic4 = (qq & 15) * 4;
            float vv[4];
            unsigned short hh[4];
#pragma unroll
            for (int e = 0; e < 4; ++e) { vv[e] = tile[(ic4 + e) * 201 + px]; hh[e] = f2bf(vv[e]); }
            int pos = (px / 14 + 1) * 16 + (px % 14 + 1);
            int byo = (pos * 128 + ic4 * 2) ^ ((pos & 7) << 4);
            *(ushort4*)(img + byo) = make_ushort4(hh[0], hh[1], hh[2], hh[3]);
        }
        for (int qq = tid; qq < 960; qq += 256) {
            int hp = qq >> 4, sub = qq & 15;
            int pos;
            if (hp < 16)      pos = hp;
            else if (hp < 32) pos = 240 + (hp - 16);
            else if (hp < 46) pos = (hp - 31) * 16;
            else              pos = (hp - 45) * 16 + 15;
            *(ushort4*)(img + pos * 128 + sub * 8) = make_ushort4(0, 0, 0, 0);
        }
    }
}

// ---------------- conv1 via MFMA 32x32x16 bf16, 2-term (unchanged from r8) -------
#define LOADB(it, BH, BL) { \
    const int o_ = ((it) >> 2) * 262144 + ((it) & 3) * 2048; \
    BH = *(const frag8*)&WHb[o_]; BL = *(const frag8*)&WLb[o_]; }

#define DOMFMA(it, BH, BL) { \
    const int tap_ = (it) >> 2; \
    const int off_ = (tap_ / 3) * 16 + (tap_ % 3); \
    const int kb_ = ((it) & 3) * 32 + q * 16; \
    frag8 aH[4]; \
    _Pragma("unroll") \
    for (int mt_ = 0; mt_ < 4; ++mt_) { \
        const int p_ = posa[mt_] + off_; \
        const int by_ = (p_ * 128 + kb_) ^ ((p_ & 7) << 4); \
        aH[mt_] = *(const frag8*)((const char*)inH + by_); \
    } \
    _Pragma("unroll") \
    for (int mt_ = 0; mt_ < 4; ++mt_) { \
        acc[mt_] = __builtin_amdgcn_mfma_f32_32x32x16_bf16(aH[mt_], BH, acc[mt_], 0, 0, 0); \
        acc[mt_] = __builtin_amdgcn_mfma_f32_32x32x16_bf16(aH[mt_], BL, acc[mt_], 0, 0, 0); \
    } }

__global__ __launch_bounds__(512, 4) void k_conv1_mfma(const unsigned short* __restrict__ imgH,
                                                       const unsigned short* __restrict__ wfh,
                                                       const unsigned short* __restrict__ wfl,
                                                       float* __restrict__ d1p) {
    __shared__ unsigned short inH[256 * 64];

    const int tid = threadIdx.x;
    const int blk = blockIdx.x;
    const int b = blk >> 5;
    const int icg = blk & 31;
    const int l = tid & 63, w = tid >> 6;
    const int ln = l & 31, q = l >> 5;
    const int mtw = w & 1, ntw = w >> 1;

    {
        const char* src = (const char*)(imgH + ((size_t)(icg * 16 + b)) * 16384);
        char* dst = (char*)inH;
#pragma unroll
        for (int k = 0; k < 4; ++k) {
            frag8 v = *(const frag8*)(src + tid * 16 + k * 8192);
            *(frag8*)(dst + tid * 16 + k * 8192) = v;
        }
    }

    acc16 acc[4];
#pragma unroll
    for (int mt = 0; mt < 4; ++mt)
#pragma unroll
        for (int r = 0; r < 16; ++r) acc[mt][r] = 0.f;

    int posa[4];
#pragma unroll
    for (int mt = 0; mt < 4; ++mt) {
        int px = mtw * 128 + mt * 32 + ln;
        posa[mt] = (px < 196) ? ((px / 14) * 16 + (px % 14)) : 0;
    }

    const unsigned short* WHb = wfh + (size_t)icg * 8192 + ntw * 512 + (size_t)l * 8;
    const unsigned short* WLb = wfl + (size_t)icg * 8192 + ntw * 512 + (size_t)l * 8;

    __syncthreads();

    frag8 B0H, B0L, B1H, B1L, B2H, B2L;
    LOADB(0, B0H, B0L);
    LOADB(1, B1H, B1L);
    LOADB(2, B2H, B2L);
#pragma unroll
    for (int g = 0; g < 12; ++g) {
        DOMFMA(g * 3 + 0, B0H, B0L); if (g < 11) LOADB(g * 3 + 3, B0H, B0L);
        DOMFMA(g * 3 + 1, B1H, B1L); if (g < 11) LOADB(g * 3 + 4, B1H, B1L);
        DOMFMA(g * 3 + 2, B2H, B2L); if (g < 11) LOADB(g * 3 + 5, B2H, B2L);
    }

    {
        float* out = d1p + (size_t)blk * D1SL;
        const int oc = ntw * 32 + ln;
#pragma unroll
        for (int mt = 0; mt < 4; ++mt) {
#pragma unroll
            for (int r = 0; r < 16; ++r) {
                int m = (r & 3) + 8 * (r >> 2) + 4 * q;
                int px = mtw * 128 + mt * 32 + m;
                if (px < 196)
                    out[px * 128 + oc] = acc[mt][r];
            }
        }
    }
}

// ---------------- reduce: d1 = relu(b1 + sum over 32 icg slices) ----------------
__global__ __launch_bounds__(256) void k_reduce(const float* __restrict__ d1p,
                                                const float* __restrict__ b1,
                                                float* __restrict__ d1) {
    int f4 = blockIdx.x * 256 + threadIdx.x;
    int flat = f4 * 4;
    int b = flat / D1SL;
    int inner = flat - b * D1SL;
    const float* src = d1p + (size_t)b * 32 * D1SL + inner;
    float4 s = *(const float4*)&b1[inner & 127];
#pragma unroll 8
    for (int icg = 0; icg < 32; ++icg) {
        float4 v = *(const float4*)&src[(size_t)icg * D1SL];
        s.x += v.x; s.y += v.y; s.z += v.z; s.w += v.w;
    }
    s.x = fmaxf(s.x, 0.f); s.y = fmaxf(s.y, 0.f);
    s.z = fmaxf(s.z, 0.f); s.w = fmaxf(s.w, 0.f);
    *(float4*)&d1[flat] = s;
}

// ---------------- conv2 + t1: grid 128 = b*8 + pt*4 + ot, 256 thr (4 waves K-split) ----
// Each block computes d2 tile [32px (pt)][32oc (ot)] for batch b; waves split K:
// wave w owns c-chunk w (ko = w*16+q*8) across 9 taps per half; 4 partials LDS-reduced.
// ot==0 blocks also compute t1 scores for px range pt*128..pt*128+127 (accum over halves).
__global__ __launch_bounds__(256, 1) void k_conv2t1(
    const float* __restrict__ d1,
    const unsigned short* __restrict__ w2fh, const unsigned short* __restrict__ w2fl,
    const float* __restrict__ b2,
    const float* __restrict__ wt1, const float* __restrict__ bt1,
    float* __restrict__ d2, float* __restrict__ score_out) {
    __shared__ unsigned short inH[304 * 72];
    __shared__ unsigned short inL[304 * 72];
    __shared__ unsigned short t1H[16 * 72];
    __shared__ unsigned short t1L[16 * 72];
    __shared__ float red[3 * 64 * 16];

    const int tid = threadIdx.x;
    const int blk = blockIdx.x;
    const int b = blk >> 3;
    const int pt = (blk >> 2) & 1;
    const int ot = blk & 3;
    const int l = tid & 63, w = tid >> 6;
    const int ln = l & 31, q = l >> 5;
    const int l16 = l & 15, q4 = l >> 4;

    acc16 c2;
    acc4 t1a[2];
#pragma unroll
    for (int r = 0; r < 16; ++r) c2[r] = 0.f;
#pragma unroll
    for (int i = 0; i < 2; ++i)
#pragma unroll
        for (int r = 0; r < 4; ++r) t1a[i][r] = 0.f;

    int posa2;
    {
        int px = pt * 32 + ln;
        posa2 = (px < 49) ? ((px / 7) * 32 + (px % 7) * 2) : 256;
    }
    const int ko = w * 16 + q * 8;

    for (int i = tid; i < 304 * 72; i += 256) { inH[i] = 0; inL[i] = 0; }
    __syncthreads();

    for (int half = 0; half < 2; ++half) {
        const int ics = half * 64;
        for (int qq = tid; qq < 3136; qq += 256) {
            int px = qq >> 4, ic4 = (qq & 15) * 4;
            float4 v = *(const float4*)&d1[(size_t)(b * 196 + px) * 128 + ics + ic4];
            float vv[4] = {fmaxf(v.x, 0.f), fmaxf(v.y, 0.f), fmaxf(v.z, 0.f), fmaxf(v.w, 0.f)};
            ushort4 h4, l4; cvt4(vv, &h4, &l4);
            int pos = (px / 14 + 1) * 16 + (px % 14 + 1);
            *(ushort4*)&inH[pos * 72 + ic4] = h4;
            *(ushort4*)&inL[pos * 72 + ic4] = l4;
        }
        if (ot == 0) {
            for (int qq = tid; qq < 1024; qq += 256) {
                int m = qq >> 6, k = qq & 63;
                float v = (m < 6) ? wt1[m * 128 + ics + k] : 0.f;
                unsigned short h = f2bf(v);
                t1H[m * 72 + k] = h;
                t1L[m * 72 + k] = f2bf(v - bf2f(h));
            }
        }
        __syncthreads();

        // 9-tap ring for this wave's c-chunk, 2-deep B prefetch from L2
        {
            const unsigned short* W2B  = w2fh + half * 8192 + w * 2048 + ot * 512 + (size_t)l * 8;
            const unsigned short* W2Bl = w2fl + half * 8192 + w * 2048 + ot * 512 + (size_t)l * 8;
            frag8 B0H = *(const frag8*)&W2B[0],     B0L = *(const frag8*)&W2Bl[0];
            frag8 B1H = *(const frag8*)&W2B[16384], B1L = *(const frag8*)&W2Bl[16384];
#pragma unroll
            for (int j = 0; j < 9; ++j) {
                const int off = (j / 3) * 16 + (j % 3);
                const int pp = (posa2 + off) * 72 + ko;
                frag8 aH = *(const frag8*)&inH[pp];
                frag8 aL = *(const frag8*)&inL[pp];
                frag8 BH = (j & 1) ? B1H : B0H;
                frag8 BL = (j & 1) ? B1L : B0L;
                c2 = __builtin_amdgcn_mfma_f32_32x32x16_bf16(aH, BH, c2, 0, 0, 0);
                c2 = __builtin_amdgcn_mfma_f32_32x32x16_bf16(aH, BL, c2, 0, 0, 0);
                c2 = __builtin_amdgcn_mfma_f32_32x32x16_bf16(aL, BH, c2, 0, 0, 0);
                if (j < 7) {
                    if (j & 1) { B1H = *(const frag8*)&W2B[(j + 2) * 16384]; B1L = *(const frag8*)&W2Bl[(j + 2) * 16384]; }
                    else       { B0H = *(const frag8*)&W2B[(j + 2) * 16384]; B0L = *(const frag8*)&W2Bl[(j + 2) * 16384]; }
                }
            }
        }

        // t1 on this half (inH intact since stage barrier)
        if (ot == 0) {
#pragma unroll
            for (int i = 0; i < 2; ++i) {
                int px = (pt * 8 + w * 2 + i) * 16 + l16;
                int pos = (px < 196) ? ((px / 14 + 1) * 16 + (px % 14 + 1)) : 256;
#pragma unroll
                for (int c = 0; c < 2; ++c) {
                    int kot = c * 32 + q4 * 8;
                    frag8 aH = *(const frag8*)&t1H[l16 * 72 + kot];
                    frag8 aL = *(const frag8*)&t1L[l16 * 72 + kot];
                    frag8 bH = *(const frag8*)&inH[pos * 72 + kot];
                    frag8 bL = *(const frag8*)&inL[pos * 72 + kot];
                    t1a[i] = __builtin_amdgcn_mfma_f32_16x16x32_bf16(aH, bH, t1a[i], 0, 0, 0);
                    t1a[i] = __builtin_amdgcn_mfma_f32_16x16x32_bf16(aH, bL, t1a[i], 0, 0, 0);
                    t1a[i] = __builtin_amdgcn_mfma_f32_16x16x32_bf16(aL, bH, t1a[i], 0, 0, 0);
                }
            }
        }
        __syncthreads();
    }

    // 4-way partial reduce + conv2 epilogue
    if (w > 0) {
#pragma unroll
        for (int r = 0; r < 16; ++r) red[((w - 1) * 64 + l) * 16 + r] = c2[r];
    }
    __syncthreads();
    if (w == 0) {
        const int oc = ot * 32 + ln;
        float bias = b2[oc];
#pragma unroll
        for (int r = 0; r < 16; ++r) {
            float s = c2[r] + red[(0 * 64 + l) * 16 + r] + red[(1 * 64 + l) * 16 + r] + red[(2 * 64 + l) * 16 + r];
            int m = (r & 3) + 8 * (r >> 2) + 4 * q;
            int px = pt * 32 + m;
            if (px < 49) d2[(size_t)(b * 49 + px) * 128 + oc] = fmaxf(s + bias, 0.f);
        }
    }
    // t1 epilogue
    if (ot == 0) {
#pragma unroll
        for (int i = 0; i < 2; ++i) {
            int px = (pt * 8 + w * 2 + i) * 16 + l16;
#pragma unroll
            for (int r = 0; r < 4; ++r) {
                int oc = q4 * 4 + r;
                if (oc < 6 && px < 196)
                    score_out[b * NA + oc * 196 + px] = t1a[i][r] + bt1[oc];
            }
        }
    }
}

// ---------------- conv3 + t2: grid 64 = b*4 + ot, 256 thr (4 waves K-split) ----------
__global__ __launch_bounds__(256, 1) void k_conv3t2(
    const float* __restrict__ d2,
    const unsigned short* __restrict__ w3fh, const unsigned short* __restrict__ w3fl,
    const float* __restrict__ b3,
    const float* __restrict__ wt2, const float* __restrict__ bt2,
    float* __restrict__ d3, float* __restrict__ score_out) {
    __shared__ unsigned short dhH[192 * 72];
    __shared__ unsigned short dhL[192 * 72];
    __shared__ unsigned short t2H[16 * 72];
    __shared__ unsigned short t2L[16 * 72];
    __shared__ float red[3 * 64 * 16];

    const int tid = threadIdx.x;
    const int blk = blockIdx.x;
    const int b = blk >> 2;
    const int ot = blk & 3;
    const int l = tid & 63, w = tid >> 6;
    const int ln = l & 31, q = l >> 5;
    const int l16 = l & 15, q4 = l >> 4;

    acc16 c3;
    acc4 t2a;
#pragma unroll
    for (int r = 0; r < 16; ++r) c3[r] = 0.f;
#pragma unroll
    for (int r = 0; r < 4; ++r) t2a[r] = 0.f;

    const int posb3 = (ln < 16) ? ((ln / 4) * 32 + (ln % 4) * 2) : 144;
    const int pxt2 = w * 16 + l16;
    const int posbt2 = (pxt2 < 49) ? ((pxt2 / 7 + 1) * 16 + (pxt2 % 7 + 1)) : 144;
    const int ko = w * 16 + q * 8;

    for (int i = tid; i < 192 * 72; i += 256) { dhH[i] = 0; dhL[i] = 0; }
    __syncthreads();

    for (int half = 0; half < 2; ++half) {
        const int ics = half * 64;
        for (int qq = tid; qq < 784; qq += 256) {
            int px = qq >> 4, ic4 = (qq & 15) * 4;
            float4 v = *(const float4*)&d2[(size_t)(b * 49 + px) * 128 + ics + ic4];
            float vv[4] = {v.x, v.y, v.z, v.w};
            ushort4 h4, l4; cvt4(vv, &h4, &l4);
            int pos = (px / 7 + 1) * 16 + (px % 7 + 1);
            *(ushort4*)&dhH[pos * 72 + ic4] = h4;
            *(ushort4*)&dhL[pos * 72 + ic4] = l4;
        }
        if (ot == 0) {
            for (int qq = tid; qq < 1024; qq += 256) {
                int m = qq >> 6, k = qq & 63;
                float v = (m < 6) ? wt2[m * 128 + ics + k] : 0.f;
                unsigned short h = f2bf(v);
                t2H[m * 72 + k] = h;
                t2L[m * 72 + k] = f2bf(v - bf2f(h));
            }
        }
        __syncthreads();

        {
            const unsigned short* W3B  = w3fh + half * 8192 + w * 2048 + ot * 512 + (size_t)l * 8;
            const unsigned short* W3Bl = w3fl + half * 8192 + w * 2048 + ot * 512 + (size_t)l * 8;
            frag8 B0H = *(const frag8*)&W3B[0],     B0L = *(const frag8*)&W3Bl[0];
            frag8 B1H = *(const frag8*)&W3B[16384], B1L = *(const frag8*)&W3Bl[16384];
#pragma unroll
            for (int j = 0; j < 9; ++j) {
                const int off = (j / 3) * 16 + (j % 3);
                const int pp = (posb3 + off) * 72 + ko;
                frag8 aH = *(const frag8*)&dhH[pp];
                frag8 aL = *(const frag8*)&dhL[pp];
                frag8 BH = (j & 1) ? B1H : B0H;
                frag8 BL = (j & 1) ? B1L : B0L;
                c3 = __builtin_amdgcn_mfma_f32_32x32x16_bf16(aH, BH, c3, 0, 0, 0);
                c3 = __builtin_amdgcn_mfma_f32_32x32x16_bf16(aH, BL, c3, 0, 0, 0);
                c3 = __builtin_amdgcn_mfma_f32_32x32x16_bf16(aL, BH, c3, 0, 0, 0);
                if (j < 7) {
                    if (j & 1) { B1H = *(const frag8*)&W3B[(j + 2) * 16384]; B1L = *(const frag8*)&W3Bl[(j + 2) * 16384]; }
                    else       { B0H = *(const frag8*)&W3B[(j + 2) * 16384]; B0L = *(const frag8*)&W3Bl[(j + 2) * 16384]; }
                }
            }
        }

        if (ot == 0) {
#pragma unroll
            for (int c = 0; c < 2; ++c) {
                int kot = c * 32 + q4 * 8;
                frag8 aH = *(const frag8*)&t2H[l16 * 72 + kot];
                frag8 aL = *(const frag8*)&t2L[l16 * 72 + kot];
                frag8 bH = *(const frag8*)&dhH[posbt2 * 72 + kot];
                frag8 bL = *(const frag8*)&dhL[posbt2 * 72 + kot];
                t2a = __builtin_amdgcn_mfma_f32_16x16x32_bf16(aH, bH, t2a, 0, 0, 0);
                t2a = __builtin_amdgcn_mfma_f32_16x16x32_bf16(aH, bL, t2a, 0, 0, 0);
                t2a = __builtin_amdgcn_mfma_f32_16x16x32_bf16(aL, bH, t2a, 0, 0, 0);
            }
        }
        __syncthreads();
    }

    if (w > 0) {
#pragma unroll
        for (int r = 0; r < 16; ++r) red[((w - 1) * 64 + l) * 16 + r] = c3[r];
    }
    __syncthreads();
    if (w == 0) {
        const int oc = ot * 32 + ln;
        float bias = b3[oc];
#pragma unroll
        for (int r = 0; r < 16; ++r) {
            float s = c3[r] + red[(0 * 64 + l) * 16 + r] + red[(1 * 64 + l) * 16 + r] + red[(2 * 64 + l) * 16 + r];
            int px = (r & 3) + 8 * (r >> 2) + 4 * q;
            if (px < 16) d3[(size_t)(b * 128 + oc) * 16 + px] = fmaxf(s + bias, 0.f);
        }
    }
    if (ot == 0) {
#pragma unroll
        for (int r = 0; r < 4; ++r) {
            int oc = q4 * 4 + r;
            if (oc < 6 && pxt2 < 49)
                score_out[b * NA + 1176 + oc * 49 + pxt2] = t2a[r] + bt2[oc];
        }
    }
}

// ---------------- t3 (VALU) + NMS: grid 16, 512 thr ----------------
__global__ __launch_bounds__(512, 1) void k_t3nms(
    const float* __restrict__ d3, const float* __restrict__ wt3, const float* __restrict__ bt3,
    const int* __restrict__ anchors, float* __restrict__ score_out,
    float* __restrict__ out_idx, float* __restrict__ out_prob, int* __restrict__ idx_ws) {
    __shared__ float wt3s[1152];
    __shared__ float d3s[2048];
    __shared__ float sbuf[NA];
    __shared__ float y0s[NA], x0s[NA], y1s[NA], x1s[NA], ars[NA];
    __shared__ float rv[8];
    __shared__ int ri[9];

    const int tid = threadIdx.x;
    const int b = blockIdx.x;
    const int l = tid & 63, w = tid >> 6;

    for (int i = tid; i < 1152; i += 512) wt3s[i] = wt3[i];
    for (int i = tid; i < 2048; i += 512) d3s[i] = d3[b * 2048 + i];
    for (int j = tid; j < 1470; j += 512) sbuf[j] = score_out[b * NA + j];
    for (int j = tid; j < NA; j += 512) {
        int4 a = ((const int4*)anchors)[j];
        float a0 = (float)a.x, a1 = (float)a.y, a2 = (float)a.z, a3 = (float)a.w;
        y0s[j] = a0; x0s[j] = a1; y1s[j] = a2; x1s[j] = a3;
        ars[j] = (a2 - a0) * (a3 - a1);
    }
    __syncthreads();

    if (tid < 144) {
        int oc = tid >> 4, px = tid & 15;
        float s = bt3[oc];
        for (int ic = 0; ic < 128; ++ic) s += wt3s[oc * 128 + ic] * d3s[ic * 16 + px];
        sbuf[1470 + oc * 16 + px] = s;
        score_out[b * NA + 1470 + oc * 16 + px] = s;
    }
    __syncthreads();

    for (int it = 0; it < TOPN; ++it) {
        float bv = -INFINITY; int bi = NA;
        for (int j = tid; j < NA; j += 512) {
            float v = sbuf[j];
            if (v > bv || (v == bv && j < bi)) { bv = v; bi = j; }
        }
#pragma unroll
        for (int d = 1; d < 64; d <<= 1) {
            float ov = __shfl_xor(bv, d, 64);
            int   oi = __shfl_xor(bi, d, 64);
            if (ov > bv || (ov == bv && oi < bi)) { bv = ov; bi = oi; }
        }
        if (l == 0) { rv[w] = bv; ri[w] = bi; }
        __syncthreads();
        if (tid == 0) {
            float V = rv[0]; int K = ri[0];
#pragma unroll
            for (int j = 1; j < 8; ++j) {
                float ov = rv[j]; int oi = ri[j];
                if (ov > V || (ov == V && oi < K)) { V = ov; K = oi; }
            }
            ri[8] = K;
            out_idx[b * TOPN + it] = (float)K;
            out_prob[b * TOPN + it] = V;
            idx_ws[b * TOPN + it] = K;
        }
        __syncthreads();
        int K = ri[8];
        float ky0 = y0s[K], kx0 = x0s[K], ky1 = y1s[K], kx1 = x1s[K], ka = ars[K];
        for (int j = tid; j < NA; j += 512) {
            float iy = fmaxf(fminf(y1s[j], ky1) - fmaxf(y0s[j], ky0), 0.f);
            float ix = fmaxf(fminf(x1s[j], kx1) - fmaxf(x0s[j], kx0), 0.f);
            float inter = iy * ix;
            float iou = inter / (ars[j] + ka - inter);
            if (iou >= 0.25f) sbuf[j] = -INFINITY;
        }
        __syncthreads();
    }
}

// ---------------- bilinear crop-resize ----------------
__global__ __launch_bounds__(256) void k_crop(const float* __restrict__ x,
                                              const int* __restrict__ anchors,
                                              const int* __restrict__ idx_ws,
                                              float* __restrict__ out) {
    int blk = blockIdx.x;
    int crop = blk / OUTS;
    int i = blk % OUTS;
    int j = threadIdx.x;
    if (j >= OUTS) return;
    int b = crop >> 2;
    int a = idx_ws[crop];
    int y0 = anchors[a * 4], x0 = anchors[a * 4 + 1];
    int y1 = anchors[a * 4 + 2], x1 = anchors[a * 4 + 3];

    float ti = (float)i / 223.f;
    float ys = (float)y0 + ti * (float)(y1 - y0 - 1);
    int yi0 = (int)ys;
    int yi1 = min(yi0 + 1, HP - 1);
    float wy = ys - (float)yi0;

    float tj = (float)j / 223.f;
    float xs = (float)x0 + tj * (float)(x1 - x0 - 1);
    int xi0 = (int)xs;
    int xi1 = min(xi0 + 1, HP - 1);
    float wx = xs - (float)xi0;

    int ry0 = yi0 - PADW, ry1 = yi1 - PADW, rx0 = xi0 - PADW, rx1 = xi1 - PADW;
    bool vy0 = (ry0 >= 0) && (ry0 < IM), vy1 = (ry1 >= 0) && (ry1 < IM);
    bool vx0 = (rx0 >= 0) && (rx0 < IM), vx1 = (rx1 >= 0) && (rx1 < IM);

    float w00 = (1.f - wy) * (1.f - wx), w01 = (1.f - wy) * wx;
    float w10 = wy * (1.f - wx), w11 = wy * wx;

#pragma unroll
    for (int c = 0; c < 3; ++c) {
        const float* xp = x + (size_t)(b * 3 + c) * IM * IM;
        float g00 = (vy0 && vx0) ? xp[ry0 * IM + rx0] : 0.f;
        float g01 = (vy0 && vx1) ? xp[ry0 * IM + rx1] : 0.f;
        float g10 = (vy1 && vx0) ? xp[ry1 * IM + rx0] : 0.f;
        float g11 = (vy1 && vx1) ? xp[ry1 * IM + rx1] : 0.f;
        out[(size_t)(crop * 3 + c) * OUTS * OUTS + i * OUTS + j] =
            g00 * w00 + g01 * w01 + g10 * w10 + g11 * w11;
    }
}

extern "C" void kernel_launch(void* const* d_in, const int* in_sizes, int n_in,
                              void* d_out, int out_size, void* d_ws, size_t ws_size,
                              hipStream_t stream) {
    (void)in_sizes; (void)n_in; (void)out_size; (void)ws_size;
    const float* x    = (const float*)d_in[0];
    const float* rpn  = (const float*)d_in[1];
    const float* w1   = (const float*)d_in[2];
    const float* b1   = (const float*)d_in[3];
    const float* w2   = (const float*)d_in[4];
    const float* b2   = (const float*)d_in[5];
    const float* w3   = (const float*)d_in[6];
    const float* b3   = (const float*)d_in[7];
    const float* wt1  = (const float*)d_in[8];
    const float* bt1  = (const float*)d_in[9];
    const float* wt2  = (const float*)d_in[10];
    const float* bt2  = (const float*)d_in[11];
    const float* wt3  = (const float*)d_in[12];
    const float* bt3  = (const float*)d_in[13];
    const int*   anc  = (const int*)d_in[14];

    float* out = (float*)d_out;
    float* ws  = (float*)d_ws;
    float* d1  = ws + WS_D1;
    int*   idxw = (int*)(ws + WS_IDX);
    unsigned short* w1h = (unsigned short*)(ws + WS_WT);
    unsigned short* w1l = w1h + NWT1;
    unsigned short* w2fh = w1l + NWT1;
    unsigned short* w2fl = w2fh + NWT2;
    unsigned short* w3fh = w2fl + NWT2;
    unsigned short* w3fl = w3fh + NWT2;
    unsigned short* imgH = w3fl + NWT2;   // NIMG ushorts
    float* d1p = (float*)(imgH + NIMG);   // 512 * 25088 floats
    float* d2  = d1p + (size_t)512 * D1SL;   // 16*49*128 floats
    float* d3  = d2 + 16 * 49 * 128;         // 16*128*16 floats

    k_prep<<<768, 256, 0, stream>>>(w1, w1h, w1l, w2, w2fh, w2fl, w3, w3fh, w3fl,
                                    rpn, imgH);
    k_conv1_mfma<<<512, 512, 0, stream>>>(imgH, w1h, w1l, d1p);
    k_reduce<<<392, 256, 0, stream>>>(d1p, b1, d1);
    k_conv2t1<<<128, 256, 0, stream>>>(d1, w2fh, w2fl, b2, wt1, bt1,
                                       d2, out + OFF_SCORE);
    k_conv3t2<<<64, 256, 0, stream>>>(d2, w3fh, w3fl, b3, wt2, bt2,
                                      d3, out + OFF_SCORE);
    k_t3nms<<<BATCH, 512, 0, stream>>>(d3, wt3, bt3, anc, out + OFF_SCORE,
                                       out + OFF_TOPIDX, out + OFF_TOPPROB, idxw);
    k_crop<<<BATCH * TOPN * OUTS, 256, 0, stream>>>(x, anc, idxw, out);
}